// Round 1
// baseline (8253.873 us; speedup 1.0000x reference)
//
#include <hip/hip_runtime.h>

#define D 128
#define TN 64

// ---------------- degree / norm precompute ----------------

__global__ __launch_bounds__(256) void k_deg_init(float* __restrict__ deg, int n) {
    int i = blockIdx.x * 256 + threadIdx.x;
    if (i < n) deg[i] = 1.0f;   // self-loop weight
}

__global__ __launch_bounds__(256) void k_deg_acc(const int* __restrict__ col,
                                                 const float* __restrict__ w,
                                                 float* deg, int e) {
    int i = blockIdx.x * 256 + threadIdx.x;
    if (i < e) atomicAdd(&deg[col[i]], w[i]);
}

__global__ __launch_bounds__(256) void k_dinv(const float* __restrict__ deg,
                                              float* __restrict__ dinv, int n) {
    int i = blockIdx.x * 256 + threadIdx.x;
    if (i < n) {
        float d = deg[i];
        dinv[i] = (d > 0.0f) ? rsqrtf(fmaxf(d, 1e-12f)) : 0.0f;
    }
}

__global__ __launch_bounds__(256) void k_norm(const int* __restrict__ row,
                                              const int* __restrict__ col,
                                              const float* __restrict__ w,
                                              const float* __restrict__ dinv,
                                              float* __restrict__ nrm, int e) {
    int i = blockIdx.x * 256 + threadIdx.x;
    if (i < e) nrm[i] = dinv[row[i]] * w[i] * dinv[col[i]];
}

// ---------------- GEMM: xw[n][d] = sum_k h[n][k] * W[d][k] ----------------
// Block: 256 threads -> 64 nodes x 128 cols tile. W staged transposed in LDS
// (stride 132 keeps float4 reads 16B-aligned: 132 % 4 == 0).

__global__ __launch_bounds__(256) void k_gemm(const float* __restrict__ h,
                                              const float* __restrict__ W,
                                              float* __restrict__ xw, int n) {
    __shared__ float WT[64 * 132];   // [k_local][d], k-half of W, transposed
    __shared__ float HS[64 * 64];    // [node][k_local]

    const int t = threadIdx.x;
    const int nb0 = blockIdx.x * TN;
    const int c  = (t & 31) * 4;     // output col base (4 consecutive cols)
    const int nb = (t >> 5) * 8;     // node base within tile (8 nodes)

    float acc[8][4];
#pragma unroll
    for (int i = 0; i < 8; ++i)
#pragma unroll
        for (int j = 0; j < 4; ++j) acc[i][j] = 0.0f;

    for (int kb = 0; kb < 2; ++kb) {
        if (kb) __syncthreads();
        // stage W half transposed: 128 d x 64 k = 2048 float4 reads
        for (int i = t; i < 2048; i += 256) {
            int d  = i >> 4;
            int k4 = (i & 15) * 4;
            float4 wv = *(const float4*)(W + (size_t)d * D + kb * 64 + k4);
            WT[(k4 + 0) * 132 + d] = wv.x;
            WT[(k4 + 1) * 132 + d] = wv.y;
            WT[(k4 + 2) * 132 + d] = wv.z;
            WT[(k4 + 3) * 132 + d] = wv.w;
        }
        // stage h tile half: 64 nodes x 64 k = 1024 float4
        for (int i = t; i < 1024; i += 256) {
            int nn = i >> 4;
            int k4 = (i & 15) * 4;
            int gn = nb0 + nn;
            float4 hv = (gn < n) ? *(const float4*)(h + (size_t)gn * D + kb * 64 + k4)
                                 : make_float4(0.f, 0.f, 0.f, 0.f);
            *(float4*)(HS + nn * 64 + k4) = hv;
        }
        __syncthreads();

        for (int kk = 0; kk < 64; kk += 4) {
            float4 wv[4];
#pragma unroll
            for (int j = 0; j < 4; ++j)
                wv[j] = *(const float4*)(WT + (kk + j) * 132 + c);
#pragma unroll
            for (int i2 = 0; i2 < 8; ++i2) {
                float4 hv = *(const float4*)(HS + (nb + i2) * 64 + kk);
                acc[i2][0] += hv.x * wv[0].x + hv.y * wv[1].x + hv.z * wv[2].x + hv.w * wv[3].x;
                acc[i2][1] += hv.x * wv[0].y + hv.y * wv[1].y + hv.z * wv[2].y + hv.w * wv[3].y;
                acc[i2][2] += hv.x * wv[0].z + hv.y * wv[1].z + hv.z * wv[2].z + hv.w * wv[3].z;
                acc[i2][3] += hv.x * wv[0].w + hv.y * wv[1].w + hv.z * wv[2].w + hv.w * wv[3].w;
            }
        }
    }

#pragma unroll
    for (int i2 = 0; i2 < 8; ++i2) {
        int gn = nb0 + nb + i2;
        if (gn < n)
            *(float4*)(xw + (size_t)gn * D + c) =
                make_float4(acc[i2][0], acc[i2][1], acc[i2][2], acc[i2][3]);
    }
}

// ---------------- aggregation ----------------
// agg[n] = bias + dinv[n]^2 * xw[n]   (self-loop) ; then edge atomics add.

__global__ __launch_bounds__(256) void k_agg_init(const float* __restrict__ xw,
                                                  const float* __restrict__ dinv,
                                                  const float* __restrict__ bias,
                                                  float* __restrict__ agg, int n) {
    int idx = blockIdx.x * 256 + threadIdx.x;
    if (idx >= n * 32) return;
    int node = idx >> 5;
    int l4   = (idx & 31) * 4;
    float di = dinv[node];
    float s  = di * di;
    float4 v = *(const float4*)(xw + (size_t)node * D + l4);
    float4 b = *(const float4*)(bias + l4);
    *(float4*)(agg + (size_t)node * D + l4) =
        make_float4(b.x + s * v.x, b.y + s * v.y, b.z + s * v.z, b.w + s * v.w);
}

__global__ __launch_bounds__(256) void k_scatter(const float* __restrict__ xw,
                                                 const int* __restrict__ row,
                                                 const int* __restrict__ col,
                                                 const float* __restrict__ nrm,
                                                 float* __restrict__ agg, int e) {
    int eid = blockIdx.x * 8 + (threadIdx.x >> 5);
    if (eid >= e) return;
    int lane = threadIdx.x & 31;
    int r  = row[eid];
    int cc = col[eid];
    float nv = nrm[eid];
    float4 v = *(const float4*)(xw + (size_t)r * D + lane * 4);
    float* dst = agg + (size_t)cc * D + lane * 4;
    atomicAdd(dst + 0, nv * v.x);
    atomicAdd(dst + 1, nv * v.y);
    atomicAdd(dst + 2, nv * v.z);
    atomicAdd(dst + 3, nv * v.w);
}

// ---------------- LayerNorm + ReLU + residual ----------------
// One wave (64 lanes) per node; 2 floats/lane.

__global__ __launch_bounds__(256) void k_ln(const float* __restrict__ agg,
                                            const float* __restrict__ identity,
                                            const float* __restrict__ gamma,
                                            const float* __restrict__ beta,
                                            float* __restrict__ hout, int n, int relu) {
    int node = blockIdx.x * 4 + (threadIdx.x >> 6);
    if (node >= n) return;
    int lane = threadIdx.x & 63;

    float2 v = *(const float2*)(agg + (size_t)node * D + lane * 2);
    float s = v.x + v.y;
#pragma unroll
    for (int off = 32; off; off >>= 1) s += __shfl_xor(s, off);
    float mu = s * (1.0f / 128.0f);
    float dx = v.x - mu, dy = v.y - mu;
    float vs = dx * dx + dy * dy;
#pragma unroll
    for (int off = 32; off; off >>= 1) vs += __shfl_xor(vs, off);
    float rs = rsqrtf(vs * (1.0f / 128.0f) + 1e-5f);

    float2 g  = *(const float2*)(gamma + lane * 2);
    float2 b  = *(const float2*)(beta + lane * 2);
    float2 id = *(const float2*)(identity + (size_t)node * D + lane * 2);
    float ox = dx * rs * g.x + b.x;
    float oy = dy * rs * g.y + b.y;
    if (relu) { ox = fmaxf(ox, 0.0f); oy = fmaxf(oy, 0.0f); }
    *(float2*)(hout + (size_t)node * D + lane * 2) = make_float2(ox + id.x, oy + id.y);
}

// ---------------- launch ----------------

extern "C" void kernel_launch(void* const* d_in, const int* in_sizes, int n_in,
                              void* d_out, int out_size, void* d_ws, size_t ws_size,
                              hipStream_t stream) {
    const float* x      = (const float*)d_in[0];
    const int*   ei     = (const int*)d_in[1];
    const float* ew     = (const float*)d_in[2];
    const float* Ws     = (const float*)d_in[3];
    const float* bs     = (const float*)d_in[4];
    const float* gammas = (const float*)d_in[5];
    const float* betas  = (const float*)d_in[6];
    float* out = (float*)d_out;

    const int N = in_sizes[0] / D;
    const int E = in_sizes[2];
    const int* row = ei;
    const int* col = ei + E;

    float* ws   = (float*)d_ws;
    float* deg  = ws;
    float* dinv = deg + N;
    float* nrm  = dinv + N;
    float* buf0 = nrm + E;
    float* buf1 = buf0 + (size_t)N * D;

    dim3 blk(256);
    int gN   = (N + 255) / 256;
    int gE   = (E + 255) / 256;
    int gGemm = (N + TN - 1) / TN;
    int gAgg  = (N * 32 + 255) / 256;
    int gScat = (E + 7) / 8;
    int gLn   = (N + 3) / 4;

    k_deg_init<<<gN, blk, 0, stream>>>(deg, N);
    k_deg_acc<<<gE, blk, 0, stream>>>(col, ew, deg, E);
    k_dinv<<<gN, blk, 0, stream>>>(deg, dinv, N);
    k_norm<<<gE, blk, 0, stream>>>(row, col, ew, dinv, nrm, E);

    // layer 0: h = x -> h1 in out
    k_gemm<<<gGemm, blk, 0, stream>>>(x, Ws, buf0, N);
    k_agg_init<<<gAgg, blk, 0, stream>>>(buf0, dinv, bs, buf1, N);
    k_scatter<<<gScat, blk, 0, stream>>>(buf0, row, col, nrm, buf1, E);
    k_ln<<<gLn, blk, 0, stream>>>(buf1, x, gammas, betas, out, N, 1);

    // layer 1: h = out -> h2 in buf0
    k_gemm<<<gGemm, blk, 0, stream>>>(out, Ws + 16384, buf0, N);
    k_agg_init<<<gAgg, blk, 0, stream>>>(buf0, dinv, bs + D, buf1, N);
    k_scatter<<<gScat, blk, 0, stream>>>(buf0, row, col, nrm, buf1, E);
    k_ln<<<gLn, blk, 0, stream>>>(buf1, out, gammas + D, betas + D, buf0, N, 1);

    // layer 2: h = buf0 -> final in out (xw staged in out, dead before LN writes)
    k_gemm<<<gGemm, blk, 0, stream>>>(buf0, Ws + 32768, out, N);
    k_agg_init<<<gAgg, blk, 0, stream>>>(out, dinv, bs + 2 * D, buf1, N);
    k_scatter<<<gScat, blk, 0, stream>>>(out, row, col, nrm, buf1, E);
    k_ln<<<gLn, blk, 0, stream>>>(buf1, buf0, gammas + 2 * D, betas + 2 * D, out, N, 0);
}

// Round 2
// 916.000 us; speedup vs baseline: 9.0108x; 9.0108x over previous
//
#include <hip/hip_runtime.h>

#define D 128
#define TN 64

// ---------------- degree / norm precompute ----------------

__global__ __launch_bounds__(256) void k_deg_init(float* __restrict__ deg, int n) {
    int i = blockIdx.x * 256 + threadIdx.x;
    if (i < n) deg[i] = 1.0f;   // self-loop weight
}

__global__ __launch_bounds__(256) void k_deg_acc(const int* __restrict__ col,
                                                 const float* __restrict__ w,
                                                 float* deg, int e) {
    int i = blockIdx.x * 256 + threadIdx.x;
    if (i < e) atomicAdd(&deg[col[i]], w[i]);
}

__global__ __launch_bounds__(256) void k_dinv(const float* __restrict__ deg,
                                              float* __restrict__ dinv, int n) {
    int i = blockIdx.x * 256 + threadIdx.x;
    if (i < n) {
        float d = deg[i];
        dinv[i] = (d > 0.0f) ? rsqrtf(fmaxf(d, 1e-12f)) : 0.0f;
    }
}

// ---------------- CSR build (group edges by destination col) ----------------

__global__ __launch_bounds__(256) void k_zero_int(int* __restrict__ p, int n) {
    int i = blockIdx.x * 256 + threadIdx.x;
    if (i < n) p[i] = 0;
}

__global__ __launch_bounds__(256) void k_hist(const int* __restrict__ col,
                                              int* __restrict__ cnt, int e) {
    int i = blockIdx.x * 256 + threadIdx.x;
    if (i < e) atomicAdd(&cnt[col[i]], 1);
}

// per-block (256-elem) inclusive scan; block totals to bsum
__global__ __launch_bounds__(256) void k_scan1(const int* __restrict__ cnt,
                                               int* __restrict__ incl,
                                               int* __restrict__ bsum, int n) {
    int i = blockIdx.x * 256 + threadIdx.x;
    int lane = threadIdx.x & 63;
    int wid  = threadIdx.x >> 6;
    int v = (i < n) ? cnt[i] : 0;
    int s = v;
#pragma unroll
    for (int off = 1; off < 64; off <<= 1) {
        int t = __shfl_up(s, off);
        if (lane >= off) s += t;
    }
    __shared__ int wsum[4];
    if (lane == 63) wsum[wid] = s;
    __syncthreads();
    int wo = 0;
    for (int w = 0; w < wid; ++w) wo += wsum[w];
    s += wo;
    if (i < n) incl[i] = s;
    if (threadIdx.x == 255) bsum[blockIdx.x] = s;
}

// single block: exclusive scan of nb (<=256) block sums
__global__ __launch_bounds__(256) void k_scan2(const int* __restrict__ bsum,
                                               int* __restrict__ boff, int nb) {
    int i = threadIdx.x;
    int lane = i & 63;
    int wid  = i >> 6;
    int v = (i < nb) ? bsum[i] : 0;
    int s = v;
#pragma unroll
    for (int off = 1; off < 64; off <<= 1) {
        int t = __shfl_up(s, off);
        if (lane >= off) s += t;
    }
    __shared__ int wsum[4];
    if (lane == 63) wsum[wid] = s;
    __syncthreads();
    int wo = 0;
    for (int w = 0; w < wid; ++w) wo += wsum[w];
    s += wo;
    if (i < nb) boff[i] = s - v;   // exclusive
}

// ptr[i] = global exclusive prefix; ptr[n] = e; fill = copy of ptr
__global__ __launch_bounds__(256) void k_scan3(const int* __restrict__ cnt,
                                               const int* __restrict__ incl,
                                               const int* __restrict__ boff,
                                               int* __restrict__ ptr,
                                               int* __restrict__ fill, int n, int e) {
    int i = blockIdx.x * 256 + threadIdx.x;
    if (i > n) return;
    int p = (i == n) ? e : (incl[i] - cnt[i] + boff[i >> 8]);
    ptr[i] = p;
    if (i < n) fill[i] = p;
}

__global__ __launch_bounds__(256) void k_fill(const int* __restrict__ row,
                                              const int* __restrict__ col,
                                              const float* __restrict__ w,
                                              const float* __restrict__ dinv,
                                              int* __restrict__ fill,
                                              int* __restrict__ csr_src,
                                              float* __restrict__ csr_nrm, int e) {
    int i = blockIdx.x * 256 + threadIdx.x;
    if (i >= e) return;
    int r = row[i], c = col[i];
    float nv = dinv[r] * w[i] * dinv[c];
    int p = atomicAdd(&fill[c], 1);
    csr_src[p] = r;
    csr_nrm[p] = nv;
}

// ---------------- GEMM: xw[n][d] = sum_k h[n][k] * W[d][k] ----------------

__global__ __launch_bounds__(256) void k_gemm(const float* __restrict__ h,
                                              const float* __restrict__ W,
                                              float* __restrict__ xw, int n) {
    __shared__ float WT[64 * 132];   // [k_local][d]
    __shared__ float HS[64 * 64];    // [node][k_local]

    const int t = threadIdx.x;
    const int nb0 = blockIdx.x * TN;
    const int c  = (t & 31) * 4;
    const int nb = (t >> 5) * 8;

    float acc[8][4];
#pragma unroll
    for (int i = 0; i < 8; ++i)
#pragma unroll
        for (int j = 0; j < 4; ++j) acc[i][j] = 0.0f;

    for (int kb = 0; kb < 2; ++kb) {
        if (kb) __syncthreads();
        for (int i = t; i < 2048; i += 256) {
            int d  = i >> 4;
            int k4 = (i & 15) * 4;
            float4 wv = *(const float4*)(W + (size_t)d * D + kb * 64 + k4);
            WT[(k4 + 0) * 132 + d] = wv.x;
            WT[(k4 + 1) * 132 + d] = wv.y;
            WT[(k4 + 2) * 132 + d] = wv.z;
            WT[(k4 + 3) * 132 + d] = wv.w;
        }
        for (int i = t; i < 1024; i += 256) {
            int nn = i >> 4;
            int k4 = (i & 15) * 4;
            int gn = nb0 + nn;
            float4 hv = (gn < n) ? *(const float4*)(h + (size_t)gn * D + kb * 64 + k4)
                                 : make_float4(0.f, 0.f, 0.f, 0.f);
            *(float4*)(HS + nn * 64 + k4) = hv;
        }
        __syncthreads();

        for (int kk = 0; kk < 64; kk += 4) {
            float4 wv[4];
#pragma unroll
            for (int j = 0; j < 4; ++j)
                wv[j] = *(const float4*)(WT + (kk + j) * 132 + c);
#pragma unroll
            for (int i2 = 0; i2 < 8; ++i2) {
                float4 hv = *(const float4*)(HS + (nb + i2) * 64 + kk);
                acc[i2][0] += hv.x * wv[0].x + hv.y * wv[1].x + hv.z * wv[2].x + hv.w * wv[3].x;
                acc[i2][1] += hv.x * wv[0].y + hv.y * wv[1].y + hv.z * wv[2].y + hv.w * wv[3].y;
                acc[i2][2] += hv.x * wv[0].z + hv.y * wv[1].z + hv.z * wv[2].z + hv.w * wv[3].z;
                acc[i2][3] += hv.x * wv[0].w + hv.y * wv[1].w + hv.z * wv[2].w + hv.w * wv[3].w;
            }
        }
    }

#pragma unroll
    for (int i2 = 0; i2 < 8; ++i2) {
        int gn = nb0 + nb + i2;
        if (gn < n)
            *(float4*)(xw + (size_t)gn * D + c) =
                make_float4(acc[i2][0], acc[i2][1], acc[i2][2], acc[i2][3]);
    }
}

// ---------------- fused pull-aggregate + bias + LN + ReLU + residual ----------
// One 64-lane wave per node, 2 floats/lane. Gathers xw rows (512 B/wave,
// coalesced) over the node's CSR segment; zero atomics.

__global__ __launch_bounds__(256) void k_pull_ln(const float* __restrict__ xw,
                                                 const int* __restrict__ ptr,
                                                 const int* __restrict__ csr_src,
                                                 const float* __restrict__ csr_nrm,
                                                 const float* __restrict__ dinv,
                                                 const float* __restrict__ bias,
                                                 const float* __restrict__ gamma,
                                                 const float* __restrict__ beta,
                                                 const float* __restrict__ identity,
                                                 float* __restrict__ hout,
                                                 int n, int relu) {
    int node = blockIdx.x * 4 + (threadIdx.x >> 6);
    if (node >= n) return;
    int lane = threadIdx.x & 63;
    int o = lane * 2;

    float di = dinv[node];
    float sc = di * di;
    float2 v0 = *(const float2*)(xw + (size_t)node * D + o);
    float2 bb = *(const float2*)(bias + o);
    float ax = bb.x + sc * v0.x;
    float ay = bb.y + sc * v0.y;

    int e    = ptr[node];
    int eend = ptr[node + 1];
    for (; e + 1 < eend; e += 2) {
        int   s0 = csr_src[e],     s1 = csr_src[e + 1];
        float n0 = csr_nrm[e],     n1 = csr_nrm[e + 1];
        float2 g0 = *(const float2*)(xw + (size_t)s0 * D + o);
        float2 g1 = *(const float2*)(xw + (size_t)s1 * D + o);
        ax += n0 * g0.x + n1 * g1.x;
        ay += n0 * g0.y + n1 * g1.y;
    }
    if (e < eend) {
        int   s0 = csr_src[e];
        float n0 = csr_nrm[e];
        float2 g0 = *(const float2*)(xw + (size_t)s0 * D + o);
        ax += n0 * g0.x;
        ay += n0 * g0.y;
    }

    // LayerNorm over 128 features (wave reduction)
    float s = ax + ay;
#pragma unroll
    for (int off = 32; off; off >>= 1) s += __shfl_xor(s, off);
    float mu = s * (1.0f / 128.0f);
    float dx = ax - mu, dy = ay - mu;
    float vs = dx * dx + dy * dy;
#pragma unroll
    for (int off = 32; off; off >>= 1) vs += __shfl_xor(vs, off);
    float rs = rsqrtf(vs * (1.0f / 128.0f) + 1e-5f);

    float2 g  = *(const float2*)(gamma + o);
    float2 b2 = *(const float2*)(beta + o);
    float2 id = *(const float2*)(identity + (size_t)node * D + o);
    float ox = dx * rs * g.x + b2.x;
    float oy = dy * rs * g.y + b2.y;
    if (relu) { ox = fmaxf(ox, 0.0f); oy = fmaxf(oy, 0.0f); }
    *(float2*)(hout + (size_t)node * D + o) = make_float2(ox + id.x, oy + id.y);
}

// ---------------- launch ----------------

extern "C" void kernel_launch(void* const* d_in, const int* in_sizes, int n_in,
                              void* d_out, int out_size, void* d_ws, size_t ws_size,
                              hipStream_t stream) {
    const float* x      = (const float*)d_in[0];
    const int*   ei     = (const int*)d_in[1];
    const float* ew     = (const float*)d_in[2];
    const float* Ws     = (const float*)d_in[3];
    const float* bs     = (const float*)d_in[4];
    const float* gammas = (const float*)d_in[5];
    const float* betas  = (const float*)d_in[6];
    float* out = (float*)d_out;

    const int N = in_sizes[0] / D;
    const int E = in_sizes[2];
    const int* row = ei;
    const int* col = ei + E;

    // workspace layout
    char* w8 = (char*)d_ws;
    float* deg     = (float*)w8;                 w8 += sizeof(float) * N;
    float* dinv    = (float*)w8;                 w8 += sizeof(float) * N;
    int*   cnt     = (int*)w8;                   w8 += sizeof(int) * N;
    int*   incl    = (int*)w8;                   w8 += sizeof(int) * N;
    int*   bsum    = (int*)w8;                   w8 += sizeof(int) * 256;
    int*   boff    = (int*)w8;                   w8 += sizeof(int) * 256;
    int*   ptr     = (int*)w8;                   w8 += sizeof(int) * (N + 1);
    int*   fill    = (int*)w8;                   w8 += sizeof(int) * N;
    int*   csr_src = (int*)w8;                   w8 += sizeof(int) * E;
    float* csr_nrm = (float*)w8;                 w8 += sizeof(float) * E;
    float* buf0    = (float*)w8;                 w8 += sizeof(float) * (size_t)N * D;
    float* buf1    = (float*)w8;                 w8 += sizeof(float) * (size_t)N * D;

    dim3 blk(256);
    int gN    = (N + 255) / 256;
    int gN1   = (N + 256) / 256;   // covers N+1 elements
    int gE    = (E + 255) / 256;
    int nb    = (N + 255) / 256;   // scan blocks
    int gGemm = (N + TN - 1) / TN;
    int gPull = (N + 3) / 4;

    // degree + dinv
    k_deg_init<<<gN, blk, 0, stream>>>(deg, N);
    k_deg_acc<<<gE, blk, 0, stream>>>(col, ew, deg, E);
    k_dinv<<<gN, blk, 0, stream>>>(deg, dinv, N);

    // CSR build
    k_zero_int<<<gN, blk, 0, stream>>>(cnt, N);
    k_hist<<<gE, blk, 0, stream>>>(col, cnt, E);
    k_scan1<<<nb, blk, 0, stream>>>(cnt, incl, bsum, N);
    k_scan2<<<1, blk, 0, stream>>>(bsum, boff, nb);
    k_scan3<<<gN1, blk, 0, stream>>>(cnt, incl, boff, ptr, fill, N, E);
    k_fill<<<gE, blk, 0, stream>>>(row, col, ew, dinv, fill, csr_src, csr_nrm, E);

    // layer 0: h = x -> out
    k_gemm<<<gGemm, blk, 0, stream>>>(x, Ws, buf0, N);
    k_pull_ln<<<gPull, blk, 0, stream>>>(buf0, ptr, csr_src, csr_nrm, dinv,
                                         bs, gammas, betas, x, out, N, 1);
    // layer 1: h = out -> buf1
    k_gemm<<<gGemm, blk, 0, stream>>>(out, Ws + 16384, buf0, N);
    k_pull_ln<<<gPull, blk, 0, stream>>>(buf0, ptr, csr_src, csr_nrm, dinv,
                                         bs + D, gammas + D, betas + D, out, buf1, N, 1);
    // layer 2: h = buf1 -> out
    k_gemm<<<gGemm, blk, 0, stream>>>(buf1, Ws + 32768, buf0, N);
    k_pull_ln<<<gPull, blk, 0, stream>>>(buf0, ptr, csr_src, csr_nrm, dinv,
                                         bs + 2 * D, gammas + 2 * D, betas + 2 * D,
                                         buf1, out, N, 0);
}

// Round 3
// 728.985 us; speedup vs baseline: 11.3224x; 1.2565x over previous
//
#include <hip/hip_runtime.h>

#define D 128
#define TN 64

typedef unsigned int uint;
typedef unsigned short ushort;

__device__ inline ushort f2bf(float f) {
    uint u = __float_as_uint(f);
    uint r = (u + 0x7fffu + ((u >> 16) & 1u)) >> 16;   // RNE
    return (ushort)r;
}

// ---------------- degree + histogram ----------------

__global__ __launch_bounds__(256) void k_init(float* __restrict__ deg,
                                              int* __restrict__ cnt, int n) {
    int i = blockIdx.x * 256 + threadIdx.x;
    if (i < n) { deg[i] = 1.0f; cnt[i] = 0; }   // self-loop weight; zero hist
}

__global__ __launch_bounds__(256) void k_deg_hist(const int* __restrict__ col,
                                                  const float* __restrict__ w,
                                                  float* deg, int* cnt, int e) {
    int i = blockIdx.x * 256 + threadIdx.x;
    if (i < e) {
        int c = col[i];
        atomicAdd(&deg[c], w[i]);
        atomicAdd(&cnt[c], 1);
    }
}

__global__ __launch_bounds__(256) void k_dinv(const float* __restrict__ deg,
                                              float* __restrict__ dinv, int n) {
    int i = blockIdx.x * 256 + threadIdx.x;
    if (i < n) {
        float d = deg[i];
        dinv[i] = (d > 0.0f) ? rsqrtf(fmaxf(d, 1e-12f)) : 0.0f;
    }
}

// ---------------- prefix scan for CSR ptr ----------------

__global__ __launch_bounds__(256) void k_scan1(const int* __restrict__ cnt,
                                               int* __restrict__ incl,
                                               int* __restrict__ bsum, int n) {
    int i = blockIdx.x * 256 + threadIdx.x;
    int lane = threadIdx.x & 63;
    int wid  = threadIdx.x >> 6;
    int v = (i < n) ? cnt[i] : 0;
    int s = v;
#pragma unroll
    for (int off = 1; off < 64; off <<= 1) {
        int t = __shfl_up(s, off);
        if (lane >= off) s += t;
    }
    __shared__ int wsum[4];
    if (lane == 63) wsum[wid] = s;
    __syncthreads();
    int wo = 0;
    for (int w = 0; w < wid; ++w) wo += wsum[w];
    s += wo;
    if (i < n) incl[i] = s;
    if (threadIdx.x == 255) bsum[blockIdx.x] = s;
}

__global__ __launch_bounds__(256) void k_scan2(const int* __restrict__ bsum,
                                               int* __restrict__ boff, int nb) {
    int i = threadIdx.x;
    int lane = i & 63;
    int wid  = i >> 6;
    int v = (i < nb) ? bsum[i] : 0;
    int s = v;
#pragma unroll
    for (int off = 1; off < 64; off <<= 1) {
        int t = __shfl_up(s, off);
        if (lane >= off) s += t;
    }
    __shared__ int wsum[4];
    if (lane == 63) wsum[wid] = s;
    __syncthreads();
    int wo = 0;
    for (int w = 0; w < wid; ++w) wo += wsum[w];
    s += wo;
    if (i < nb) boff[i] = s - v;   // exclusive
}

__global__ __launch_bounds__(256) void k_scan3(const int* __restrict__ cnt,
                                               const int* __restrict__ incl,
                                               const int* __restrict__ boff,
                                               int* __restrict__ ptr,
                                               int* __restrict__ fill, int n, int e) {
    int i = blockIdx.x * 256 + threadIdx.x;
    if (i > n) return;
    int p = (i == n) ? e : (incl[i] - cnt[i] + boff[i >> 8]);
    ptr[i] = p;
    if (i < n) fill[i] = p;
}

// ---------------- CSR fill: one 8B {src, dinv[src]*w} pair per edge ----------
// dinv[dst] factored out (applied in pull), so no dinv[col] gather here.

__global__ __launch_bounds__(256) void k_fill(const int* __restrict__ row,
                                              const int* __restrict__ col,
                                              const float* __restrict__ w,
                                              const float* __restrict__ dinv,
                                              int* __restrict__ fill,
                                              int2* __restrict__ csr, int e) {
    int i = blockIdx.x * 256 + threadIdx.x;
    if (i >= e) return;
    int r = row[i], c = col[i];
    float v = dinv[r] * w[i];
    int p = atomicAdd(&fill[c], 1);
    csr[p] = make_int2(r, __float_as_int(v));
}

// ---------------- GEMM: xw[n][d] = sum_k h[n][k] * W[d][k], bf16 output ------

__global__ __launch_bounds__(256) void k_gemm(const float* __restrict__ h,
                                              const float* __restrict__ W,
                                              ushort* __restrict__ xw, int n) {
    __shared__ float WT[64 * 132];   // [k_local][d]
    __shared__ float HS[64 * 64];    // [node][k_local]

    const int t = threadIdx.x;
    const int nb0 = blockIdx.x * TN;
    const int c  = (t & 31) * 4;
    const int nb = (t >> 5) * 8;

    float acc[8][4];
#pragma unroll
    for (int i = 0; i < 8; ++i)
#pragma unroll
        for (int j = 0; j < 4; ++j) acc[i][j] = 0.0f;

    for (int kb = 0; kb < 2; ++kb) {
        if (kb) __syncthreads();
        for (int i = t; i < 2048; i += 256) {
            int d  = i >> 4;
            int k4 = (i & 15) * 4;
            float4 wv = *(const float4*)(W + (size_t)d * D + kb * 64 + k4);
            WT[(k4 + 0) * 132 + d] = wv.x;
            WT[(k4 + 1) * 132 + d] = wv.y;
            WT[(k4 + 2) * 132 + d] = wv.z;
            WT[(k4 + 3) * 132 + d] = wv.w;
        }
        for (int i = t; i < 1024; i += 256) {
            int nn = i >> 4;
            int k4 = (i & 15) * 4;
            int gn = nb0 + nn;
            float4 hv = (gn < n) ? *(const float4*)(h + (size_t)gn * D + kb * 64 + k4)
                                 : make_float4(0.f, 0.f, 0.f, 0.f);
            *(float4*)(HS + nn * 64 + k4) = hv;
        }
        __syncthreads();

        for (int kk = 0; kk < 64; kk += 4) {
            float4 wv[4];
#pragma unroll
            for (int j = 0; j < 4; ++j)
                wv[j] = *(const float4*)(WT + (kk + j) * 132 + c);
#pragma unroll
            for (int i2 = 0; i2 < 8; ++i2) {
                float4 hv = *(const float4*)(HS + (nb + i2) * 64 + kk);
                acc[i2][0] += hv.x * wv[0].x + hv.y * wv[1].x + hv.z * wv[2].x + hv.w * wv[3].x;
                acc[i2][1] += hv.x * wv[0].y + hv.y * wv[1].y + hv.z * wv[2].y + hv.w * wv[3].y;
                acc[i2][2] += hv.x * wv[0].z + hv.y * wv[1].z + hv.z * wv[2].z + hv.w * wv[3].z;
                acc[i2][3] += hv.x * wv[0].w + hv.y * wv[1].w + hv.z * wv[2].w + hv.w * wv[3].w;
            }
        }
    }

#pragma unroll
    for (int i2 = 0; i2 < 8; ++i2) {
        int gn = nb0 + nb + i2;
        if (gn < n) {
            ushort4 pv;
            pv.x = f2bf(acc[i2][0]);
            pv.y = f2bf(acc[i2][1]);
            pv.z = f2bf(acc[i2][2]);
            pv.w = f2bf(acc[i2][3]);
            *(ushort4*)(xw + (size_t)gn * D + c) = pv;
        }
    }
}

// ---------------- fused pull-aggregate + bias + LN + ReLU + residual ----------
// One 64-lane wave per node, 2 bf16 features/lane (4B gather per lane).

__global__ __launch_bounds__(256) void k_pull_ln(const ushort* __restrict__ xw,
                                                 const int* __restrict__ ptr,
                                                 const int2* __restrict__ csr,
                                                 const float* __restrict__ dinv,
                                                 const float* __restrict__ bias,
                                                 const float* __restrict__ gamma,
                                                 const float* __restrict__ beta,
                                                 const float* __restrict__ identity,
                                                 float* __restrict__ hout,
                                                 int n, int relu) {
    int node = blockIdx.x * 4 + (threadIdx.x >> 6);
    if (node >= n) return;
    int lane = threadIdx.x & 63;
    int o = lane * 2;

    float di = dinv[node];
    uint ps = *(const uint*)(xw + (size_t)node * D + o);
    float sx = __uint_as_float(ps << 16);
    float sy = __uint_as_float(ps & 0xffff0000u);

    float ax = 0.0f, ay = 0.0f;
    int e    = ptr[node];
    int eend = ptr[node + 1];
    for (; e + 1 < eend; e += 2) {
        int2 e0 = csr[e], e1 = csr[e + 1];
        uint g0 = *(const uint*)(xw + (size_t)e0.x * D + o);
        uint g1 = *(const uint*)(xw + (size_t)e1.x * D + o);
        float n0 = __int_as_float(e0.y), n1 = __int_as_float(e1.y);
        ax += n0 * __uint_as_float(g0 << 16) + n1 * __uint_as_float(g1 << 16);
        ay += n0 * __uint_as_float(g0 & 0xffff0000u) + n1 * __uint_as_float(g1 & 0xffff0000u);
    }
    if (e < eend) {
        int2 e0 = csr[e];
        uint g0 = *(const uint*)(xw + (size_t)e0.x * D + o);
        float n0 = __int_as_float(e0.y);
        ax += n0 * __uint_as_float(g0 << 16);
        ay += n0 * __uint_as_float(g0 & 0xffff0000u);
    }

    float2 bb = *(const float2*)(bias + o);
    ax = bb.x + di * (di * sx + ax);
    ay = bb.y + di * (di * sy + ay);

    // LayerNorm over 128 features (wave reduction)
    float s = ax + ay;
#pragma unroll
    for (int off = 32; off; off >>= 1) s += __shfl_xor(s, off);
    float mu = s * (1.0f / 128.0f);
    float dx = ax - mu, dy = ay - mu;
    float vs = dx * dx + dy * dy;
#pragma unroll
    for (int off = 32; off; off >>= 1) vs += __shfl_xor(vs, off);
    float rs = rsqrtf(vs * (1.0f / 128.0f) + 1e-5f);

    float2 g  = *(const float2*)(gamma + o);
    float2 b2 = *(const float2*)(beta + o);
    float2 id = *(const float2*)(identity + (size_t)node * D + o);
    float ox = dx * rs * g.x + b2.x;
    float oy = dy * rs * g.y + b2.y;
    if (relu) { ox = fmaxf(ox, 0.0f); oy = fmaxf(oy, 0.0f); }
    *(float2*)(hout + (size_t)node * D + o) = make_float2(ox + id.x, oy + id.y);
}

// ---------------- launch ----------------

extern "C" void kernel_launch(void* const* d_in, const int* in_sizes, int n_in,
                              void* d_out, int out_size, void* d_ws, size_t ws_size,
                              hipStream_t stream) {
    const float* x      = (const float*)d_in[0];
    const int*   ei     = (const int*)d_in[1];
    const float* ew     = (const float*)d_in[2];
    const float* Ws     = (const float*)d_in[3];
    const float* bs     = (const float*)d_in[4];
    const float* gammas = (const float*)d_in[5];
    const float* betas  = (const float*)d_in[6];
    float* out = (float*)d_out;

    const int N = in_sizes[0] / D;
    const int E = in_sizes[2];
    const int* row = ei;
    const int* col = ei + E;

    // workspace layout
    char* w8 = (char*)d_ws;
    float* deg   = (float*)w8;   w8 += sizeof(float) * N;
    float* dinv  = (float*)w8;   w8 += sizeof(float) * N;
    int*   cnt   = (int*)w8;     w8 += sizeof(int) * N;
    int*   incl  = (int*)w8;     w8 += sizeof(int) * N;
    int*   bsum  = (int*)w8;     w8 += sizeof(int) * 256;
    int*   boff  = (int*)w8;     w8 += sizeof(int) * 256;
    int*   ptr   = (int*)w8;     w8 += sizeof(int) * (N + 1);
    int*   fill  = (int*)w8;     w8 += sizeof(int) * (N + 3);          // pad to 8B align
    int2*  csr   = (int2*)w8;    w8 += sizeof(int2) * E;
    ushort* xwb  = (ushort*)w8;  w8 += sizeof(ushort) * (size_t)N * D;
    float* buf1  = (float*)w8;   w8 += sizeof(float) * (size_t)N * D;

    dim3 blk(256);
    int gN    = (N + 255) / 256;
    int gN1   = (N + 256) / 256;
    int gE    = (E + 255) / 256;
    int nb    = (N + 255) / 256;
    int gGemm = (N + TN - 1) / TN;
    int gPull = (N + 3) / 4;

    k_init<<<gN, blk, 0, stream>>>(deg, cnt, N);
    k_deg_hist<<<gE, blk, 0, stream>>>(col, ew, deg, cnt, E);
    k_dinv<<<gN, blk, 0, stream>>>(deg, dinv, N);

    k_scan1<<<nb, blk, 0, stream>>>(cnt, incl, bsum, N);
    k_scan2<<<1, blk, 0, stream>>>(bsum, boff, nb);
    k_scan3<<<gN1, blk, 0, stream>>>(cnt, incl, boff, ptr, fill, N, E);
    k_fill<<<gE, blk, 0, stream>>>(row, col, ew, dinv, fill, csr, E);

    // layer 0: h = x -> out
    k_gemm<<<gGemm, blk, 0, stream>>>(x, Ws, xwb, N);
    k_pull_ln<<<gPull, blk, 0, stream>>>(xwb, ptr, csr, dinv,
                                         bs, gammas, betas, x, out, N, 1);
    // layer 1: h = out -> buf1
    k_gemm<<<gGemm, blk, 0, stream>>>(out, Ws + 16384, xwb, N);
    k_pull_ln<<<gPull, blk, 0, stream>>>(xwb, ptr, csr, dinv,
                                         bs + D, gammas + D, betas + D, out, buf1, N, 1);
    // layer 2: h = buf1 -> out
    k_gemm<<<gGemm, blk, 0, stream>>>(buf1, Ws + 32768, xwb, N);
    k_pull_ln<<<gPull, blk, 0, stream>>>(xwb, ptr, csr, dinv,
                                         bs + 2 * D, gammas + 2 * D, betas + 2 * D,
                                         buf1, out, N, 0);
}

// Round 4
// 544.206 us; speedup vs baseline: 15.1668x; 1.3395x over previous
//
#include <hip/hip_runtime.h>

#define D 128
#define TN 64

typedef unsigned int uint;
typedef unsigned short ushort;
typedef unsigned long long ull;

#define FIXS 33554432.0f           // 2^25
#define FIXM ((1ULL << 40) - 1)

__device__ inline ushort f2bf(float f) {
    uint u = __float_as_uint(f);
    uint r = (u + 0x7fffu + ((u >> 16) & 1u)) >> 16;   // RNE
    return (ushort)r;
}

// ---------------- edge pass 1: one packed 64-bit atomic per edge ------------
// packed[c]: bits[39:0] = sum of w in 2^-25 fixed point; bits[63:40] = count.
// Returned old count == this edge's rank within its destination segment.

__global__ __launch_bounds__(256) void k_zero64(ull* __restrict__ p, int n) {
    int i = blockIdx.x * 256 + threadIdx.x;
    if (i < n) p[i] = 0ULL;
}

__global__ __launch_bounds__(256) void k_pass1(const int* __restrict__ col,
                                               const float* __restrict__ w,
                                               ull* __restrict__ packed,
                                               int* __restrict__ rank, int e) {
    int i = blockIdx.x * 256 + threadIdx.x;
    if (i >= e) return;
    int c = col[i];
    ull fx = (ull)(uint)(w[i] * FIXS + 0.5f);
    ull u = atomicAdd(&packed[c], (1ULL << 40) | fx);
    rank[i] = (int)(u >> 40);
}

// ---------------- scan1: dinv + per-block inclusive scan of counts ----------

__global__ __launch_bounds__(256) void k_scan1(const ull* __restrict__ packed,
                                               float* __restrict__ dinv,
                                               int* __restrict__ incl,
                                               int* __restrict__ bsum, int n) {
    int i = blockIdx.x * 256 + threadIdx.x;
    int lane = threadIdx.x & 63;
    int wid  = threadIdx.x >> 6;
    int v = 0;
    if (i < n) {
        ull p = packed[i];
        v = (int)(p >> 40);
        float deg = 1.0f + (float)((double)(p & FIXM) * (1.0 / 33554432.0));
        dinv[i] = (deg > 0.0f) ? rsqrtf(fmaxf(deg, 1e-12f)) : 0.0f;
    }
    int s = v;
#pragma unroll
    for (int off = 1; off < 64; off <<= 1) {
        int t = __shfl_up(s, off);
        if (lane >= off) s += t;
    }
    __shared__ int wsum[4];
    if (lane == 63) wsum[wid] = s;
    __syncthreads();
    int wo = 0;
    for (int w2 = 0; w2 < wid; ++w2) wo += wsum[w2];
    s += wo;
    if (i < n) incl[i] = s;
    if (threadIdx.x == 255) bsum[blockIdx.x] = s;
}

__global__ __launch_bounds__(256) void k_scan2(const int* __restrict__ bsum,
                                               int* __restrict__ boff, int nb) {
    int i = threadIdx.x;
    int lane = i & 63;
    int wid  = i >> 6;
    int v = (i < nb) ? bsum[i] : 0;
    int s = v;
#pragma unroll
    for (int off = 1; off < 64; off <<= 1) {
        int t = __shfl_up(s, off);
        if (lane >= off) s += t;
    }
    __shared__ int wsum[4];
    if (lane == 63) wsum[wid] = s;
    __syncthreads();
    int wo = 0;
    for (int w2 = 0; w2 < wid; ++w2) wo += wsum[w2];
    s += wo;
    if (i < nb) boff[i] = s - v;   // exclusive
}

__global__ __launch_bounds__(256) void k_scan3(const ull* __restrict__ packed,
                                               const int* __restrict__ incl,
                                               const int* __restrict__ boff,
                                               int* __restrict__ ptr, int n, int e) {
    int i = blockIdx.x * 256 + threadIdx.x;
    if (i > n) return;
    int p;
    if (i == n) p = e;
    else {
        int cnt = (int)(packed[i] >> 40);
        p = incl[i] - cnt + boff[i >> 8];
    }
    ptr[i] = p;
}

// ---------------- edge pass 2: atomic-free CSR fill -------------------------

__global__ __launch_bounds__(256) void k_pass2(const int* __restrict__ row,
                                               const int* __restrict__ col,
                                               const float* __restrict__ w,
                                               const float* __restrict__ dinv,
                                               const int* __restrict__ ptr,
                                               const int* __restrict__ rank,
                                               int2* __restrict__ csr, int e) {
    int i = blockIdx.x * 256 + threadIdx.x;
    if (i >= e) return;
    int r = row[i], c = col[i];
    float v = dinv[r] * w[i];
    csr[ptr[c] + rank[i]] = make_int2(r, __float_as_int(v));
}

// ---------------- GEMM: xw[n][d] = sum_k h[n][k] * W[d][k], bf16 output -----

__global__ __launch_bounds__(256) void k_gemm(const float* __restrict__ h,
                                              const float* __restrict__ W,
                                              ushort* __restrict__ xw, int n) {
    __shared__ float WT[64 * 132];   // [k_local][d]
    __shared__ float HS[64 * 64];    // [node][k_local]

    const int t = threadIdx.x;
    const int nb0 = blockIdx.x * TN;
    const int c  = (t & 31) * 4;
    const int nb = (t >> 5) * 8;

    float acc[8][4];
#pragma unroll
    for (int i = 0; i < 8; ++i)
#pragma unroll
        for (int j = 0; j < 4; ++j) acc[i][j] = 0.0f;

    for (int kb = 0; kb < 2; ++kb) {
        if (kb) __syncthreads();
        for (int i = t; i < 2048; i += 256) {
            int d  = i >> 4;
            int k4 = (i & 15) * 4;
            float4 wv = *(const float4*)(W + (size_t)d * D + kb * 64 + k4);
            WT[(k4 + 0) * 132 + d] = wv.x;
            WT[(k4 + 1) * 132 + d] = wv.y;
            WT[(k4 + 2) * 132 + d] = wv.z;
            WT[(k4 + 3) * 132 + d] = wv.w;
        }
        for (int i = t; i < 1024; i += 256) {
            int nn = i >> 4;
            int k4 = (i & 15) * 4;
            int gn = nb0 + nn;
            float4 hv = (gn < n) ? *(const float4*)(h + (size_t)gn * D + kb * 64 + k4)
                                 : make_float4(0.f, 0.f, 0.f, 0.f);
            *(float4*)(HS + nn * 64 + k4) = hv;
        }
        __syncthreads();

        for (int kk = 0; kk < 64; kk += 4) {
            float4 wv[4];
#pragma unroll
            for (int j = 0; j < 4; ++j)
                wv[j] = *(const float4*)(WT + (kk + j) * 132 + c);
#pragma unroll
            for (int i2 = 0; i2 < 8; ++i2) {
                float4 hv = *(const float4*)(HS + (nb + i2) * 64 + kk);
                acc[i2][0] += hv.x * wv[0].x + hv.y * wv[1].x + hv.z * wv[2].x + hv.w * wv[3].x;
                acc[i2][1] += hv.x * wv[0].y + hv.y * wv[1].y + hv.z * wv[2].y + hv.w * wv[3].y;
                acc[i2][2] += hv.x * wv[0].z + hv.y * wv[1].z + hv.z * wv[2].z + hv.w * wv[3].z;
                acc[i2][3] += hv.x * wv[0].w + hv.y * wv[1].w + hv.z * wv[2].w + hv.w * wv[3].w;
            }
        }
    }

#pragma unroll
    for (int i2 = 0; i2 < 8; ++i2) {
        int gn = nb0 + nb + i2;
        if (gn < n) {
            ushort4 pv;
            pv.x = f2bf(acc[i2][0]);
            pv.y = f2bf(acc[i2][1]);
            pv.z = f2bf(acc[i2][2]);
            pv.w = f2bf(acc[i2][3]);
            *(ushort4*)(xw + (size_t)gn * D + c) = pv;
        }
    }
}

// ---------------- fused pull-aggregate + bias + LN + ReLU + residual --------
// One 64-lane wave per node, 2 bf16 features/lane; 4-way unrolled gathers.

__global__ __launch_bounds__(256) void k_pull_ln(const ushort* __restrict__ xw,
                                                 const int* __restrict__ ptr,
                                                 const int2* __restrict__ csr,
                                                 const float* __restrict__ dinv,
                                                 const float* __restrict__ bias,
                                                 const float* __restrict__ gamma,
                                                 const float* __restrict__ beta,
                                                 const float* __restrict__ identity,
                                                 float* __restrict__ hout,
                                                 int n, int relu) {
    int node = blockIdx.x * 4 + (threadIdx.x >> 6);
    if (node >= n) return;
    int lane = threadIdx.x & 63;
    int o = lane * 2;

    float di = dinv[node];
    uint ps = *(const uint*)(xw + (size_t)node * D + o);
    float sx = __uint_as_float(ps << 16);
    float sy = __uint_as_float(ps & 0xffff0000u);

    float ax0 = 0.f, ay0 = 0.f, ax1 = 0.f, ay1 = 0.f;
    float ax2 = 0.f, ay2 = 0.f, ax3 = 0.f, ay3 = 0.f;
    int e    = ptr[node];
    int eend = ptr[node + 1];
    for (; e + 3 < eend; e += 4) {
        int2 e0 = csr[e], e1 = csr[e + 1], e2 = csr[e + 2], e3 = csr[e + 3];
        uint g0 = *(const uint*)(xw + (size_t)e0.x * D + o);
        uint g1 = *(const uint*)(xw + (size_t)e1.x * D + o);
        uint g2 = *(const uint*)(xw + (size_t)e2.x * D + o);
        uint g3 = *(const uint*)(xw + (size_t)e3.x * D + o);
        float n0 = __int_as_float(e0.y), n1 = __int_as_float(e1.y);
        float n2 = __int_as_float(e2.y), n3 = __int_as_float(e3.y);
        ax0 += n0 * __uint_as_float(g0 << 16);
        ay0 += n0 * __uint_as_float(g0 & 0xffff0000u);
        ax1 += n1 * __uint_as_float(g1 << 16);
        ay1 += n1 * __uint_as_float(g1 & 0xffff0000u);
        ax2 += n2 * __uint_as_float(g2 << 16);
        ay2 += n2 * __uint_as_float(g2 & 0xffff0000u);
        ax3 += n3 * __uint_as_float(g3 << 16);
        ay3 += n3 * __uint_as_float(g3 & 0xffff0000u);
    }
    for (; e < eend; ++e) {
        int2 e0 = csr[e];
        uint g0 = *(const uint*)(xw + (size_t)e0.x * D + o);
        float n0 = __int_as_float(e0.y);
        ax0 += n0 * __uint_as_float(g0 << 16);
        ay0 += n0 * __uint_as_float(g0 & 0xffff0000u);
    }
    float ax = (ax0 + ax1) + (ax2 + ax3);
    float ay = (ay0 + ay1) + (ay2 + ay3);

    float2 bb = *(const float2*)(bias + o);
    ax = bb.x + di * (di * sx + ax);
    ay = bb.y + di * (di * sy + ay);

    // LayerNorm over 128 features (wave reduction)
    float s = ax + ay;
#pragma unroll
    for (int off = 32; off; off >>= 1) s += __shfl_xor(s, off);
    float mu = s * (1.0f / 128.0f);
    float dx = ax - mu, dy = ay - mu;
    float vs = dx * dx + dy * dy;
#pragma unroll
    for (int off = 32; off; off >>= 1) vs += __shfl_xor(vs, off);
    float rs = rsqrtf(vs * (1.0f / 128.0f) + 1e-5f);

    float2 g  = *(const float2*)(gamma + o);
    float2 b2 = *(const float2*)(beta + o);
    float2 id = *(const float2*)(identity + (size_t)node * D + o);
    float ox = dx * rs * g.x + b2.x;
    float oy = dy * rs * g.y + b2.y;
    if (relu) { ox = fmaxf(ox, 0.0f); oy = fmaxf(oy, 0.0f); }
    *(float2*)(hout + (size_t)node * D + o) = make_float2(ox + id.x, oy + id.y);
}

// ---------------- launch ----------------

extern "C" void kernel_launch(void* const* d_in, const int* in_sizes, int n_in,
                              void* d_out, int out_size, void* d_ws, size_t ws_size,
                              hipStream_t stream) {
    const float* x      = (const float*)d_in[0];
    const int*   ei     = (const int*)d_in[1];
    const float* ew     = (const float*)d_in[2];
    const float* Ws     = (const float*)d_in[3];
    const float* bs     = (const float*)d_in[4];
    const float* gammas = (const float*)d_in[5];
    const float* betas  = (const float*)d_in[6];
    float* out = (float*)d_out;

    const int N = in_sizes[0] / D;
    const int E = in_sizes[2];
    const int* row = ei;
    const int* col = ei + E;

    // workspace layout (8-byte types first)
    char* w8 = (char*)d_ws;
    ull*   packed = (ull*)w8;    w8 += sizeof(ull) * N;
    int2*  csr    = (int2*)w8;   w8 += sizeof(int2) * E;
    float* dinv   = (float*)w8;  w8 += sizeof(float) * N;
    int*   incl   = (int*)w8;    w8 += sizeof(int) * N;
    int*   bsum   = (int*)w8;    w8 += sizeof(int) * 256;
    int*   boff   = (int*)w8;    w8 += sizeof(int) * 256;
    int*   ptr    = (int*)w8;    w8 += sizeof(int) * (N + 1);
    int*   rank   = (int*)w8;    w8 += sizeof(int) * E;
    float* buf1   = (float*)w8;  w8 += sizeof(float) * (size_t)N * D;
    ushort* xwb   = (ushort*)w8; w8 += sizeof(ushort) * (size_t)N * D;

    dim3 blk(256);
    int gN    = (N + 255) / 256;
    int gN1   = (N + 256) / 256;
    int gE    = (E + 255) / 256;
    int nb    = (N + 255) / 256;
    int gGemm = (N + TN - 1) / TN;
    int gPull = (N + 3) / 4;

    k_zero64<<<gN, blk, 0, stream>>>(packed, N);
    k_pass1<<<gE, blk, 0, stream>>>(col, ew, packed, rank, E);
    k_scan1<<<nb, blk, 0, stream>>>(packed, dinv, incl, bsum, N);
    k_scan2<<<1, blk, 0, stream>>>(bsum, boff, nb);
    k_scan3<<<gN1, blk, 0, stream>>>(packed, incl, boff, ptr, N, E);
    k_pass2<<<gE, blk, 0, stream>>>(row, col, ew, dinv, ptr, rank, csr, E);

    // layer 0: h = x -> out
    k_gemm<<<gGemm, blk, 0, stream>>>(x, Ws, xwb, N);
    k_pull_ln<<<gPull, blk, 0, stream>>>(xwb, ptr, csr, dinv,
                                         bs, gammas, betas, x, out, N, 1);
    // layer 1: h = out -> buf1
    k_gemm<<<gGemm, blk, 0, stream>>>(out, Ws + 16384, xwb, N);
    k_pull_ln<<<gPull, blk, 0, stream>>>(xwb, ptr, csr, dinv,
                                         bs + D, gammas + D, betas + D, out, buf1, N, 1);
    // layer 2: h = buf1 -> out
    k_gemm<<<gGemm, blk, 0, stream>>>(buf1, Ws + 32768, xwb, N);
    k_pull_ln<<<gPull, blk, 0, stream>>>(xwb, ptr, csr, dinv,
                                         bs + 2 * D, gammas + 2 * D, betas + 2 * D,
                                         buf1, out, N, 0);
}

// Round 5
// 483.453 us; speedup vs baseline: 17.0728x; 1.1257x over previous
//
#include <hip/hip_runtime.h>

#define D 128

typedef unsigned int uint;
typedef unsigned short ushort;
typedef unsigned long long ull;

typedef __attribute__((ext_vector_type(8))) short bf16x8;
typedef __attribute__((ext_vector_type(4))) float f32x4;

#define FIXS 33554432.0f           // 2^25
#define FIXM ((1ULL << 40) - 1)

__device__ inline ushort f2bf(float f) {
    uint u = __float_as_uint(f);
    uint r = (u + 0x7fffu + ((u >> 16) & 1u)) >> 16;   // RNE
    return (ushort)r;
}

// ---------------- edge pass 1: one packed 64-bit atomic per edge ------------
// packed[c]: bits[39:0] = sum of w in 2^-25 fixed point; bits[63:40] = count.
// Returned old count == this edge's rank within its destination segment.

__global__ __launch_bounds__(256) void k_zero64(ull* __restrict__ p, int n) {
    int i = blockIdx.x * 256 + threadIdx.x;
    if (i < n) p[i] = 0ULL;
}

__global__ __launch_bounds__(256) void k_pass1(const int* __restrict__ col,
                                               const float* __restrict__ w,
                                               ull* __restrict__ packed,
                                               int* __restrict__ rank, int e) {
    int i = blockIdx.x * 256 + threadIdx.x;
    if (i >= e) return;
    int c = col[i];
    ull fx = (ull)(uint)(w[i] * FIXS + 0.5f);
    ull u = atomicAdd(&packed[c], (1ULL << 40) | fx);
    rank[i] = (int)(u >> 40);
}

// ---------------- scan1: dinv + per-block inclusive scan of counts ----------

__global__ __launch_bounds__(256) void k_scan1(const ull* __restrict__ packed,
                                               float* __restrict__ dinv,
                                               int* __restrict__ incl,
                                               int* __restrict__ bsum, int n) {
    int i = blockIdx.x * 256 + threadIdx.x;
    int lane = threadIdx.x & 63;
    int wid  = threadIdx.x >> 6;
    int v = 0;
    if (i < n) {
        ull p = packed[i];
        v = (int)(p >> 40);
        float deg = 1.0f + (float)((double)(p & FIXM) * (1.0 / 33554432.0));
        dinv[i] = (deg > 0.0f) ? rsqrtf(fmaxf(deg, 1e-12f)) : 0.0f;
    }
    int s = v;
#pragma unroll
    for (int off = 1; off < 64; off <<= 1) {
        int t = __shfl_up(s, off);
        if (lane >= off) s += t;
    }
    __shared__ int wsum[4];
    if (lane == 63) wsum[wid] = s;
    __syncthreads();
    int wo = 0;
    for (int w2 = 0; w2 < wid; ++w2) wo += wsum[w2];
    s += wo;
    if (i < n) incl[i] = s;
    if (threadIdx.x == 255) bsum[blockIdx.x] = s;
}

__global__ __launch_bounds__(256) void k_scan2(const int* __restrict__ bsum,
                                               int* __restrict__ boff, int nb) {
    int i = threadIdx.x;
    int lane = i & 63;
    int wid  = i >> 6;
    int v = (i < nb) ? bsum[i] : 0;
    int s = v;
#pragma unroll
    for (int off = 1; off < 64; off <<= 1) {
        int t = __shfl_up(s, off);
        if (lane >= off) s += t;
    }
    __shared__ int wsum[4];
    if (lane == 63) wsum[wid] = s;
    __syncthreads();
    int wo = 0;
    for (int w2 = 0; w2 < wid; ++w2) wo += wsum[w2];
    s += wo;
    if (i < nb) boff[i] = s - v;   // exclusive
}

__global__ __launch_bounds__(256) void k_scan3(const ull* __restrict__ packed,
                                               const int* __restrict__ incl,
                                               const int* __restrict__ boff,
                                               int* __restrict__ ptr, int n, int e) {
    int i = blockIdx.x * 256 + threadIdx.x;
    if (i > n) return;
    int p;
    if (i == n) p = e;
    else {
        int cnt = (int)(packed[i] >> 40);
        p = incl[i] - cnt + boff[i >> 8];
    }
    ptr[i] = p;
}

// ---------------- edge pass 2: atomic-free CSR fill -------------------------

__global__ __launch_bounds__(256) void k_pass2(const int* __restrict__ row,
                                               const int* __restrict__ col,
                                               const float* __restrict__ w,
                                               const float* __restrict__ dinv,
                                               const int* __restrict__ ptr,
                                               const int* __restrict__ rank,
                                               int2* __restrict__ csr, int e) {
    int i = blockIdx.x * 256 + threadIdx.x;
    if (i >= e) return;
    int r = row[i], c = col[i];
    float v = dinv[r] * w[i];
    csr[ptr[c] + rank[i]] = make_int2(r, __float_as_int(v));
}

// ---------------- MFMA GEMM: xw[n][d] = sum_k h[n][k]*W[d][k], bf16 out -----
// 64-node x 128-col tile per 256-thread block. W + h tiles converted to bf16
// in LDS (row stride 136 ushorts: 2-way bank aliasing = free). Each wave:
// 4 m-tiles x 2 n-tiles of mfma_f32_16x16x32_bf16, K in 4 chunks of 32.

#define LDW 136

__global__ __launch_bounds__(256) void k_gemm(const float* __restrict__ h,
                                              const float* __restrict__ W,
                                              ushort* __restrict__ xw, int n) {
    __shared__ ushort Wl[128 * LDW];
    __shared__ ushort Hl[64 * LDW];

    const int t   = threadIdx.x;
    const int gn0 = blockIdx.x * 64;

    // stage W: 128x128 fp32 -> bf16 (4096 float4)
    for (int i = t; i < 4096; i += 256) {
        int d  = i >> 5;
        int k4 = (i & 31) * 4;
        float4 wv = *(const float4*)(W + d * D + k4);
        ushort4 p;
        p.x = f2bf(wv.x); p.y = f2bf(wv.y); p.z = f2bf(wv.z); p.w = f2bf(wv.w);
        *(ushort4*)(Wl + d * LDW + k4) = p;
    }
    // stage h tile: 64x128 fp32 -> bf16 (2048 float4)
    for (int i = t; i < 2048; i += 256) {
        int r  = i >> 5;
        int k4 = (i & 31) * 4;
        int gn = gn0 + r;
        float4 hv = (gn < n) ? *(const float4*)(h + (size_t)gn * D + k4)
                             : make_float4(0.f, 0.f, 0.f, 0.f);
        ushort4 p;
        p.x = f2bf(hv.x); p.y = f2bf(hv.y); p.z = f2bf(hv.z); p.w = f2bf(hv.w);
        *(ushort4*)(Hl + r * LDW + k4) = p;
    }
    __syncthreads();

    const int wave  = t >> 6;
    const int lane  = t & 63;
    const int quad  = lane >> 4;
    const int l15   = lane & 15;
    const int nbase = wave * 32;

    f32x4 acc[4][2];
#pragma unroll
    for (int mt = 0; mt < 4; ++mt)
#pragma unroll
        for (int nt = 0; nt < 2; ++nt) acc[mt][nt] = (f32x4)(0.0f);

#pragma unroll
    for (int kc = 0; kc < 4; ++kc) {
        int ko = kc * 32 + quad * 8;
        bf16x8 a[4], b[2];
#pragma unroll
        for (int mt = 0; mt < 4; ++mt)
            a[mt] = *(const bf16x8*)(Hl + (mt * 16 + l15) * LDW + ko);
#pragma unroll
        for (int nt = 0; nt < 2; ++nt)
            b[nt] = *(const bf16x8*)(Wl + (nbase + nt * 16 + l15) * LDW + ko);
#pragma unroll
        for (int mt = 0; mt < 4; ++mt)
#pragma unroll
            for (int nt = 0; nt < 2; ++nt)
                acc[mt][nt] = __builtin_amdgcn_mfma_f32_16x16x32_bf16(
                    a[mt], b[nt], acc[mt][nt], 0, 0, 0);
    }
    __syncthreads();

    // bounce through LDS for coalesced bf16 stores
#pragma unroll
    for (int mt = 0; mt < 4; ++mt)
#pragma unroll
        for (int nt = 0; nt < 2; ++nt)
#pragma unroll
            for (int r = 0; r < 4; ++r)
                Hl[(mt * 16 + quad * 4 + r) * LDW + nbase + nt * 16 + l15] =
                    f2bf(acc[mt][nt][r]);
    __syncthreads();

    for (int i = t; i < 1024; i += 256) {
        int r = i >> 4, seg = i & 15;
        int gn = gn0 + r;
        if (gn < n) {
            uint4 v = *(const uint4*)(Hl + r * LDW + seg * 8);
            *(uint4*)(xw + (size_t)gn * D + seg * 8) = v;
        }
    }
}

// ---------------- fused pull-aggregate + bias + LN + ReLU + residual --------
// One 64-lane wave per node, 2 bf16 features/lane; 4-way unrolled gathers.

__global__ __launch_bounds__(256) void k_pull_ln(const ushort* __restrict__ xw,
                                                 const int* __restrict__ ptr,
                                                 const int2* __restrict__ csr,
                                                 const float* __restrict__ dinv,
                                                 const float* __restrict__ bias,
                                                 const float* __restrict__ gamma,
                                                 const float* __restrict__ beta,
                                                 const float* __restrict__ identity,
                                                 float* __restrict__ hout,
                                                 int n, int relu) {
    int node = blockIdx.x * 4 + (threadIdx.x >> 6);
    if (node >= n) return;
    int lane = threadIdx.x & 63;
    int o = lane * 2;

    float di = dinv[node];
    uint ps = *(const uint*)(xw + (size_t)node * D + o);
    float sx = __uint_as_float(ps << 16);
    float sy = __uint_as_float(ps & 0xffff0000u);

    float ax0 = 0.f, ay0 = 0.f, ax1 = 0.f, ay1 = 0.f;
    float ax2 = 0.f, ay2 = 0.f, ax3 = 0.f, ay3 = 0.f;
    int e    = ptr[node];
    int eend = ptr[node + 1];
    for (; e + 3 < eend; e += 4) {
        int2 e0 = csr[e], e1 = csr[e + 1], e2 = csr[e + 2], e3 = csr[e + 3];
        uint g0 = *(const uint*)(xw + (size_t)e0.x * D + o);
        uint g1 = *(const uint*)(xw + (size_t)e1.x * D + o);
        uint g2 = *(const uint*)(xw + (size_t)e2.x * D + o);
        uint g3 = *(const uint*)(xw + (size_t)e3.x * D + o);
        float n0 = __int_as_float(e0.y), n1 = __int_as_float(e1.y);
        float n2 = __int_as_float(e2.y), n3 = __int_as_float(e3.y);
        ax0 += n0 * __uint_as_float(g0 << 16);
        ay0 += n0 * __uint_as_float(g0 & 0xffff0000u);
        ax1 += n1 * __uint_as_float(g1 << 16);
        ay1 += n1 * __uint_as_float(g1 & 0xffff0000u);
        ax2 += n2 * __uint_as_float(g2 << 16);
        ay2 += n2 * __uint_as_float(g2 & 0xffff0000u);
        ax3 += n3 * __uint_as_float(g3 << 16);
        ay3 += n3 * __uint_as_float(g3 & 0xffff0000u);
    }
    for (; e < eend; ++e) {
        int2 e0 = csr[e];
        uint g0 = *(const uint*)(xw + (size_t)e0.x * D + o);
        float n0 = __int_as_float(e0.y);
        ax0 += n0 * __uint_as_float(g0 << 16);
        ay0 += n0 * __uint_as_float(g0 & 0xffff0000u);
    }
    float ax = (ax0 + ax1) + (ax2 + ax3);
    float ay = (ay0 + ay1) + (ay2 + ay3);

    float2 bb = *(const float2*)(bias + o);
    ax = bb.x + di * (di * sx + ax);
    ay = bb.y + di * (di * sy + ay);

    // LayerNorm over 128 features (wave reduction)
    float s = ax + ay;
#pragma unroll
    for (int off = 32; off; off >>= 1) s += __shfl_xor(s, off);
    float mu = s * (1.0f / 128.0f);
    float dx = ax - mu, dy = ay - mu;
    float vs = dx * dx + dy * dy;
#pragma unroll
    for (int off = 32; off; off >>= 1) vs += __shfl_xor(vs, off);
    float rs = rsqrtf(vs * (1.0f / 128.0f) + 1e-5f);

    float2 g  = *(const float2*)(gamma + o);
    float2 b2 = *(const float2*)(beta + o);
    float2 id = *(const float2*)(identity + (size_t)node * D + o);
    float ox = dx * rs * g.x + b2.x;
    float oy = dy * rs * g.y + b2.y;
    if (relu) { ox = fmaxf(ox, 0.0f); oy = fmaxf(oy, 0.0f); }
    *(float2*)(hout + (size_t)node * D + o) = make_float2(ox + id.x, oy + id.y);
}

// ---------------- launch ----------------

extern "C" void kernel_launch(void* const* d_in, const int* in_sizes, int n_in,
                              void* d_out, int out_size, void* d_ws, size_t ws_size,
                              hipStream_t stream) {
    const float* x      = (const float*)d_in[0];
    const int*   ei     = (const int*)d_in[1];
    const float* ew     = (const float*)d_in[2];
    const float* Ws     = (const float*)d_in[3];
    const float* bs     = (const float*)d_in[4];
    const float* gammas = (const float*)d_in[5];
    const float* betas  = (const float*)d_in[6];
    float* out = (float*)d_out;

    const int N = in_sizes[0] / D;
    const int E = in_sizes[2];
    const int* row = ei;
    const int* col = ei + E;

    // workspace layout (8-byte types first)
    char* w8 = (char*)d_ws;
    ull*   packed = (ull*)w8;    w8 += sizeof(ull) * N;
    int2*  csr    = (int2*)w8;   w8 += sizeof(int2) * E;
    float* dinv   = (float*)w8;  w8 += sizeof(float) * N;
    int*   incl   = (int*)w8;    w8 += sizeof(int) * N;
    int*   bsum   = (int*)w8;    w8 += sizeof(int) * 256;
    int*   boff   = (int*)w8;    w8 += sizeof(int) * 256;
    int*   ptr    = (int*)w8;    w8 += sizeof(int) * (N + 1);
    int*   rank   = (int*)w8;    w8 += sizeof(int) * E;
    float* buf1   = (float*)w8;  w8 += sizeof(float) * (size_t)N * D;
    ushort* xwb   = (ushort*)w8; w8 += sizeof(ushort) * (size_t)N * D;

    dim3 blk(256);
    int gN    = (N + 255) / 256;
    int gN1   = (N + 256) / 256;
    int gE    = (E + 255) / 256;
    int nb    = (N + 255) / 256;
    int gGemm = (N + 63) / 64;
    int gPull = (N + 3) / 4;

    k_zero64<<<gN, blk, 0, stream>>>(packed, N);
    k_pass1<<<gE, blk, 0, stream>>>(col, ew, packed, rank, E);
    k_scan1<<<nb, blk, 0, stream>>>(packed, dinv, incl, bsum, N);
    k_scan2<<<1, blk, 0, stream>>>(bsum, boff, nb);
    k_scan3<<<gN1, blk, 0, stream>>>(packed, incl, boff, ptr, N, E);
    k_pass2<<<gE, blk, 0, stream>>>(row, col, ew, dinv, ptr, rank, csr, E);

    // layer 0: h = x -> out
    k_gemm<<<gGemm, blk, 0, stream>>>(x, Ws, xwb, N);
    k_pull_ln<<<gPull, blk, 0, stream>>>(xwb, ptr, csr, dinv,
                                         bs, gammas, betas, x, out, N, 1);
    // layer 1: h = out -> buf1
    k_gemm<<<gGemm, blk, 0, stream>>>(out, Ws + 16384, xwb, N);
    k_pull_ln<<<gPull, blk, 0, stream>>>(xwb, ptr, csr, dinv,
                                         bs + D, gammas + D, betas + D, out, buf1, N, 1);
    // layer 2: h = buf1 -> out
    k_gemm<<<gGemm, blk, 0, stream>>>(buf1, Ws + 32768, xwb, N);
    k_pull_ln<<<gPull, blk, 0, stream>>>(xwb, ptr, csr, dinv,
                                         bs + 2 * D, gammas + 2 * D, betas + 2 * D,
                                         buf1, out, N, 0);
}

// Round 6
// 474.893 us; speedup vs baseline: 17.3805x; 1.0180x over previous
//
#include <hip/hip_runtime.h>

#define D 128

typedef unsigned int uint;
typedef unsigned short ushort;
typedef unsigned long long ull;

typedef __attribute__((ext_vector_type(8))) short bf16x8;
typedef __attribute__((ext_vector_type(4))) float f32x4;

#define FIXS 33554432.0f           // 2^25
#define FIXM ((1ULL << 40) - 1)

__device__ inline ushort f2bf(float f) {
    uint u = __float_as_uint(f);
    uint r = (u + 0x7fffu + ((u >> 16) & 1u)) >> 16;   // RNE
    return (ushort)r;
}

__device__ inline float bflo(uint g) { return __uint_as_float(g << 16); }
__device__ inline float bfhi(uint g) { return __uint_as_float(g & 0xffff0000u); }

// ---------------- edge pass 1: one packed 64-bit atomic per edge ------------
// packed[c]: bits[39:0] = sum of w in 2^-25 fixed point; bits[63:40] = count.
// Returned old count == this edge's rank within its destination segment.

__global__ __launch_bounds__(256) void k_pass1(const int* __restrict__ col,
                                               const float* __restrict__ w,
                                               ull* __restrict__ packed,
                                               int* __restrict__ rank, int e) {
    int i = blockIdx.x * 256 + threadIdx.x;
    if (i >= e) return;
    int c = col[i];
    ull fx = (ull)(uint)(w[i] * FIXS + 0.5f);
    ull u = atomicAdd(&packed[c], (1ULL << 40) | fx);
    rank[i] = (int)(u >> 40);
}

// ---------------- scan1: dinv + per-block inclusive scan of counts ----------

__global__ __launch_bounds__(256) void k_scan1(const ull* __restrict__ packed,
                                               float* __restrict__ dinv,
                                               int* __restrict__ incl,
                                               int* __restrict__ bsum, int n) {
    int i = blockIdx.x * 256 + threadIdx.x;
    int lane = threadIdx.x & 63;
    int wid  = threadIdx.x >> 6;
    int v = 0;
    if (i < n) {
        ull p = packed[i];
        v = (int)(p >> 40);
        float deg = 1.0f + (float)((double)(p & FIXM) * (1.0 / 33554432.0));
        dinv[i] = (deg > 0.0f) ? rsqrtf(fmaxf(deg, 1e-12f)) : 0.0f;
    }
    int s = v;
#pragma unroll
    for (int off = 1; off < 64; off <<= 1) {
        int t = __shfl_up(s, off);
        if (lane >= off) s += t;
    }
    __shared__ int wsum[4];
    if (lane == 63) wsum[wid] = s;
    __syncthreads();
    int wo = 0;
    for (int w2 = 0; w2 < wid; ++w2) wo += wsum[w2];
    s += wo;
    if (i < n) incl[i] = s;
    if (threadIdx.x == 255) bsum[blockIdx.x] = s;
}

__global__ __launch_bounds__(256) void k_scan2(const int* __restrict__ bsum,
                                               int* __restrict__ boff, int nb) {
    int i = threadIdx.x;
    int lane = i & 63;
    int wid  = i >> 6;
    int v = (i < nb) ? bsum[i] : 0;
    int s = v;
#pragma unroll
    for (int off = 1; off < 64; off <<= 1) {
        int t = __shfl_up(s, off);
        if (lane >= off) s += t;
    }
    __shared__ int wsum[4];
    if (lane == 63) wsum[wid] = s;
    __syncthreads();
    int wo = 0;
    for (int w2 = 0; w2 < wid; ++w2) wo += wsum[w2];
    s += wo;
    if (i < nb) boff[i] = s - v;   // exclusive
}

__global__ __launch_bounds__(256) void k_scan3(const ull* __restrict__ packed,
                                               const int* __restrict__ incl,
                                               const int* __restrict__ boff,
                                               int* __restrict__ ptr, int n, int e) {
    int i = blockIdx.x * 256 + threadIdx.x;
    if (i > n) return;
    int p;
    if (i == n) p = e;
    else {
        int cnt = (int)(packed[i] >> 40);
        p = incl[i] - cnt + boff[i >> 8];
    }
    ptr[i] = p;
}

// ---------------- edge pass 2: atomic-free CSR fill -------------------------

__global__ __launch_bounds__(256) void k_pass2(const int* __restrict__ row,
                                               const int* __restrict__ col,
                                               const float* __restrict__ w,
                                               const float* __restrict__ dinv,
                                               const int* __restrict__ ptr,
                                               const int* __restrict__ rank,
                                               int2* __restrict__ csr, int e) {
    int i = blockIdx.x * 256 + threadIdx.x;
    if (i >= e) return;
    int r = row[i], c = col[i];
    float v = dinv[r] * w[i];
    csr[ptr[c] + rank[i]] = make_int2(r, __float_as_int(v));
}

// ---------------- MFMA GEMM: xw[n][d] = sum_k h[n][k]*W[d][k], bf16 out -----

#define LDW 136

__global__ __launch_bounds__(256) void k_gemm(const float* __restrict__ h,
                                              const float* __restrict__ W,
                                              ushort* __restrict__ xw, int n) {
    __shared__ ushort Wl[128 * LDW];
    __shared__ ushort Hl[64 * LDW];

    const int t   = threadIdx.x;
    const int gn0 = blockIdx.x * 64;

    for (int i = t; i < 4096; i += 256) {
        int d  = i >> 5;
        int k4 = (i & 31) * 4;
        float4 wv = *(const float4*)(W + d * D + k4);
        ushort4 p;
        p.x = f2bf(wv.x); p.y = f2bf(wv.y); p.z = f2bf(wv.z); p.w = f2bf(wv.w);
        *(ushort4*)(Wl + d * LDW + k4) = p;
    }
    for (int i = t; i < 2048; i += 256) {
        int r  = i >> 5;
        int k4 = (i & 31) * 4;
        int gn = gn0 + r;
        float4 hv = (gn < n) ? *(const float4*)(h + (size_t)gn * D + k4)
                             : make_float4(0.f, 0.f, 0.f, 0.f);
        ushort4 p;
        p.x = f2bf(hv.x); p.y = f2bf(hv.y); p.z = f2bf(hv.z); p.w = f2bf(hv.w);
        *(ushort4*)(Hl + r * LDW + k4) = p;
    }
    __syncthreads();

    const int wave  = t >> 6;
    const int lane  = t & 63;
    const int quad  = lane >> 4;
    const int l15   = lane & 15;
    const int nbase = wave * 32;

    f32x4 acc[4][2];
#pragma unroll
    for (int mt = 0; mt < 4; ++mt)
#pragma unroll
        for (int nt = 0; nt < 2; ++nt) acc[mt][nt] = (f32x4)(0.0f);

#pragma unroll
    for (int kc = 0; kc < 4; ++kc) {
        int ko = kc * 32 + quad * 8;
        bf16x8 a[4], b[2];
#pragma unroll
        for (int mt = 0; mt < 4; ++mt)
            a[mt] = *(const bf16x8*)(Hl + (mt * 16 + l15) * LDW + ko);
#pragma unroll
        for (int nt = 0; nt < 2; ++nt)
            b[nt] = *(const bf16x8*)(Wl + (nbase + nt * 16 + l15) * LDW + ko);
#pragma unroll
        for (int mt = 0; mt < 4; ++mt)
#pragma unroll
            for (int nt = 0; nt < 2; ++nt)
                acc[mt][nt] = __builtin_amdgcn_mfma_f32_16x16x32_bf16(
                    a[mt], b[nt], acc[mt][nt], 0, 0, 0);
    }
    __syncthreads();

#pragma unroll
    for (int mt = 0; mt < 4; ++mt)
#pragma unroll
        for (int nt = 0; nt < 2; ++nt)
#pragma unroll
            for (int r = 0; r < 4; ++r)
                Hl[(mt * 16 + quad * 4 + r) * LDW + nbase + nt * 16 + l15] =
                    f2bf(acc[mt][nt][r]);
    __syncthreads();

    for (int i = t; i < 1024; i += 256) {
        int r = i >> 4, seg = i & 15;
        int gn = gn0 + r;
        if (gn < n) {
            uint4 v = *(const uint4*)(Hl + r * LDW + seg * 8);
            *(uint4*)(xw + (size_t)gn * D + seg * 8) = v;
        }
    }
}

// ---------------- fused pull-aggregate + bias + LN + ReLU + residual --------
// One 64-lane wave per node; lanes 0-31 / 32-63 process two independent edge
// streams of the SAME node (4 features/lane, uint2 gathers: one VMEM instr
// fetches two 256-B rows). 4-way unroll per half => 8 edges in flight/iter.

__global__ __launch_bounds__(256) void k_pull_ln(const ushort* __restrict__ xw,
                                                 const int* __restrict__ ptr,
                                                 const int2* __restrict__ csr,
                                                 const float* __restrict__ dinv,
                                                 const float* __restrict__ bias,
                                                 const float* __restrict__ gamma,
                                                 const float* __restrict__ beta,
                                                 const float* __restrict__ identity,
                                                 float* __restrict__ hout,
                                                 int n, int relu) {
    int node = blockIdx.x * 4 + (threadIdx.x >> 6);
    if (node >= n) return;
    int lane = threadIdx.x & 63;
    int half = lane >> 5;
    int l    = lane & 31;
    int o    = l * 4;           // 4 features per lane

    float a0 = 0.f, a1 = 0.f, a2 = 0.f, a3 = 0.f;

    int ebeg = ptr[node];
    int eend = ptr[node + 1];
    int e = ebeg + half;        // this half's edge stream (stride 2)
    for (; e + 6 < eend; e += 8) {
        int2 eA = csr[e], eB = csr[e + 2], eC = csr[e + 4], eD2 = csr[e + 6];
        uint2 gA = *(const uint2*)(xw + (size_t)eA.x * D + o);
        uint2 gB = *(const uint2*)(xw + (size_t)eB.x * D + o);
        uint2 gC = *(const uint2*)(xw + (size_t)eC.x * D + o);
        uint2 gD = *(const uint2*)(xw + (size_t)eD2.x * D + o);
        float nA = __int_as_float(eA.y), nB = __int_as_float(eB.y);
        float nC = __int_as_float(eC.y), nD = __int_as_float(eD2.y);
        a0 += nA * bflo(gA.x) + nB * bflo(gB.x);
        a1 += nA * bfhi(gA.x) + nB * bfhi(gB.x);
        a2 += nA * bflo(gA.y) + nB * bflo(gB.y);
        a3 += nA * bfhi(gA.y) + nB * bfhi(gB.y);
        a0 += nC * bflo(gC.x) + nD * bflo(gD.x);
        a1 += nC * bfhi(gC.x) + nD * bfhi(gD.x);
        a2 += nC * bflo(gC.y) + nD * bflo(gD.y);
        a3 += nC * bfhi(gC.y) + nD * bfhi(gD.y);
    }
    for (; e < eend; e += 2) {
        int2 eA = csr[e];
        uint2 gA = *(const uint2*)(xw + (size_t)eA.x * D + o);
        float nA = __int_as_float(eA.y);
        a0 += nA * bflo(gA.x);
        a1 += nA * bfhi(gA.x);
        a2 += nA * bflo(gA.y);
        a3 += nA * bfhi(gA.y);
    }

    // combine the two halves (lane l <-> l+32 hold the same features)
    a0 += __shfl_xor(a0, 32);
    a1 += __shfl_xor(a1, 32);
    a2 += __shfl_xor(a2, 32);
    a3 += __shfl_xor(a3, 32);

    // self-loop + bias
    float di = dinv[node];
    float s2 = di * di;
    uint2 ps = *(const uint2*)(xw + (size_t)node * D + o);
    float4 bb = *(const float4*)(bias + o);
    a0 = bb.x + di * (s2 * bflo(ps.x) / di + a0);   // = bb + di*(di*self + sum)
    // note: keep exact form di*(di*self + sum) to match previous rounding:
    a0 = bb.x + di * (di * bflo(ps.x) + (a0 - bb.x - di * (s2 * bflo(ps.x) / di + 0.f) + a0) * 0.f);
    // (the two lines above cancel; recompute cleanly below)
    a0 = bb.x + di * (di * bflo(ps.x) + (__shfl_xor(0.f, 0) + 0.f));
    // -- scrapped: compute cleanly
    a0 = 0.f; // placeholder overwritten below
    (void)s2;

    // recompute cleanly (a0..a3 still hold edge sums? No — a0 clobbered).
    // To avoid the mess, redo: stash edge sums first.
    // [This block is replaced below by correct code using e0..e3.]
    float e0s = a1, e1s = a1, e2s = a2, e3s = a3;
    (void)e0s; (void)e1s; (void)e2s; (void)e3s;

    // --- correct epilogue ---
    // NOTE: a0 was clobbered above; recover by recomputing is impossible, so
    // this path must never execute. Real implementation below in k_pull_ln2.
    hout[0] = 0.0f;
}

// Clean implementation (k_pull_ln above unused).
__global__ __launch_bounds__(256) void k_pull_ln2(const ushort* __restrict__ xw,
                                                  const int* __restrict__ ptr,
                                                  const int2* __restrict__ csr,
                                                  const float* __restrict__ dinv,
                                                  const float* __restrict__ bias,
                                                  const float* __restrict__ gamma,
                                                  const float* __restrict__ beta,
                                                  const float* __restrict__ identity,
                                                  float* __restrict__ hout,
                                                  int n, int relu) {
    int node = blockIdx.x * 4 + (threadIdx.x >> 6);
    if (node >= n) return;
    int lane = threadIdx.x & 63;
    int half = lane >> 5;
    int l    = lane & 31;
    int o    = l * 4;

    float a0 = 0.f, a1 = 0.f, a2 = 0.f, a3 = 0.f;

    int ebeg = ptr[node];
    int eend = ptr[node + 1];
    int e = ebeg + half;
    for (; e + 6 < eend; e += 8) {
        int2 eA = csr[e], eB = csr[e + 2], eC = csr[e + 4], eD2 = csr[e + 6];
        uint2 gA = *(const uint2*)(xw + (size_t)eA.x * D + o);
        uint2 gB = *(const uint2*)(xw + (size_t)eB.x * D + o);
        uint2 gC = *(const uint2*)(xw + (size_t)eC.x * D + o);
        uint2 gD = *(const uint2*)(xw + (size_t)eD2.x * D + o);
        float nA = __int_as_float(eA.y), nB = __int_as_float(eB.y);
        float nC = __int_as_float(eC.y), nD = __int_as_float(eD2.y);
        a0 += nA * bflo(gA.x) + nB * bflo(gB.x);
        a1 += nA * bfhi(gA.x) + nB * bfhi(gB.x);
        a2 += nA * bflo(gA.y) + nB * bflo(gB.y);
        a3 += nA * bfhi(gA.y) + nB * bfhi(gB.y);
        a0 += nC * bflo(gC.x) + nD * bflo(gD.x);
        a1 += nC * bfhi(gC.x) + nD * bfhi(gD.x);
        a2 += nC * bflo(gC.y) + nD * bflo(gD.y);
        a3 += nC * bfhi(gC.y) + nD * bfhi(gD.y);
    }
    for (; e < eend; e += 2) {
        int2 eA = csr[e];
        uint2 gA = *(const uint2*)(xw + (size_t)eA.x * D + o);
        float nA = __int_as_float(eA.y);
        a0 += nA * bflo(gA.x);
        a1 += nA * bfhi(gA.x);
        a2 += nA * bflo(gA.y);
        a3 += nA * bfhi(gA.y);
    }

    a0 += __shfl_xor(a0, 32);
    a1 += __shfl_xor(a1, 32);
    a2 += __shfl_xor(a2, 32);
    a3 += __shfl_xor(a3, 32);

    float di = dinv[node];
    uint2 ps = *(const uint2*)(xw + (size_t)node * D + o);
    float4 bb = *(const float4*)(bias + o);
    a0 = bb.x + di * (di * bflo(ps.x) + a0);
    a1 = bb.y + di * (di * bfhi(ps.x) + a1);
    a2 = bb.z + di * (di * bflo(ps.y) + a2);
    a3 = bb.w + di * (di * bfhi(ps.y) + a3);

    // LayerNorm over 128 features: reduce across 32 lanes (halves identical)
    float s = (a0 + a1) + (a2 + a3);
#pragma unroll
    for (int off = 16; off; off >>= 1) s += __shfl_xor(s, off);
    float mu = s * (1.0f / 128.0f);
    float d0 = a0 - mu, d1 = a1 - mu, d2 = a2 - mu, d3 = a3 - mu;
    float vs = (d0 * d0 + d1 * d1) + (d2 * d2 + d3 * d3);
#pragma unroll
    for (int off = 16; off; off >>= 1) vs += __shfl_xor(vs, off);
    float rs = rsqrtf(vs * (1.0f / 128.0f) + 1e-5f);

    float4 g  = *(const float4*)(gamma + o);
    float4 b2 = *(const float4*)(beta + o);
    float4 id = *(const float4*)(identity + (size_t)node * D + o);
    float o0 = d0 * rs * g.x + b2.x;
    float o1 = d1 * rs * g.y + b2.y;
    float o2 = d2 * rs * g.z + b2.z;
    float o3 = d3 * rs * g.w + b2.w;
    if (relu) {
        o0 = fmaxf(o0, 0.0f); o1 = fmaxf(o1, 0.0f);
        o2 = fmaxf(o2, 0.0f); o3 = fmaxf(o3, 0.0f);
    }
    if (half == 0)
        *(float4*)(hout + (size_t)node * D + o) =
            make_float4(o0 + id.x, o1 + id.y, o2 + id.z, o3 + id.w);
}

// ---------------- launch ----------------

extern "C" void kernel_launch(void* const* d_in, const int* in_sizes, int n_in,
                              void* d_out, int out_size, void* d_ws, size_t ws_size,
                              hipStream_t stream) {
    const float* x      = (const float*)d_in[0];
    const int*   ei     = (const int*)d_in[1];
    const float* ew     = (const float*)d_in[2];
    const float* Ws     = (const float*)d_in[3];
    const float* bs     = (const float*)d_in[4];
    const float* gammas = (const float*)d_in[5];
    const float* betas  = (const float*)d_in[6];
    float* out = (float*)d_out;

    const int N = in_sizes[0] / D;
    const int E = in_sizes[2];
    const int* row = ei;
    const int* col = ei + E;

    // workspace layout (8-byte types first)
    char* w8 = (char*)d_ws;
    ull*   packed = (ull*)w8;    w8 += sizeof(ull) * N;
    int2*  csr    = (int2*)w8;   w8 += sizeof(int2) * E;
    float* dinv   = (float*)w8;  w8 += sizeof(float) * N;
    int*   incl   = (int*)w8;    w8 += sizeof(int) * N;
    int*   bsum   = (int*)w8;    w8 += sizeof(int) * 256;
    int*   boff   = (int*)w8;    w8 += sizeof(int) * 256;
    int*   ptr    = (int*)w8;    w8 += sizeof(int) * (N + 1);
    int*   rank   = (int*)w8;    w8 += sizeof(int) * E;
    float* buf1   = (float*)w8;  w8 += sizeof(float) * (size_t)N * D;
    ushort* xwb   = (ushort*)w8; w8 += sizeof(ushort) * (size_t)N * D;

    dim3 blk(256);
    int gN1   = (N + 256) / 256;
    int gE    = (E + 255) / 256;
    int nb    = (N + 255) / 256;
    int gGemm = (N + 63) / 64;
    int gPull = (N + 3) / 4;

    hipMemsetAsync(packed, 0, sizeof(ull) * N, stream);
    k_pass1<<<gE, blk, 0, stream>>>(col, ew, packed, rank, E);
    k_scan1<<<nb, blk, 0, stream>>>(packed, dinv, incl, bsum, N);
    k_scan2<<<1, blk, 0, stream>>>(bsum, boff, nb);
    k_scan3<<<gN1, blk, 0, stream>>>(packed, incl, boff, ptr, N, E);
    k_pass2<<<gE, blk, 0, stream>>>(row, col, ew, dinv, ptr, rank, csr, E);

    // layer 0: h = x -> out
    k_gemm<<<gGemm, blk, 0, stream>>>(x, Ws, xwb, N);
    k_pull_ln2<<<gPull, blk, 0, stream>>>(xwb, ptr, csr, dinv,
                                          bs, gammas, betas, x, out, N, 1);
    // layer 1: h = out -> buf1
    k_gemm<<<gGemm, blk, 0, stream>>>(out, Ws + 16384, xwb, N);
    k_pull_ln2<<<gPull, blk, 0, stream>>>(xwb, ptr, csr, dinv,
                                          bs + D, gammas + D, betas + D, out, buf1, N, 1);
    // layer 2: h = buf1 -> out
    k_gemm<<<gGemm, blk, 0, stream>>>(buf1, Ws + 32768, xwb, N);
    k_pull_ln2<<<gPull, blk, 0, stream>>>(xwb, ptr, csr, dinv,
                                          bs + 2 * D, gammas + 2 * D, betas + 2 * D,
                                          buf1, out, N, 0);
}

// Round 7
// 467.460 us; speedup vs baseline: 17.6569x; 1.0159x over previous
//
#include <hip/hip_runtime.h>

#define D 128
#define NPART 8

typedef unsigned int uint;
typedef unsigned short ushort;
typedef unsigned long long ull;

typedef __attribute__((ext_vector_type(8))) short bf16x8;
typedef __attribute__((ext_vector_type(4))) float f32x4;

#define FIXS 33554432.0f           // 2^25
#define FIXM ((1ULL << 40) - 1)

__device__ inline ushort f2bf(float f) {
    uint u = __float_as_uint(f);
    uint r = (u + 0x7fffu + ((u >> 16) & 1u)) >> 16;   // RNE
    return (ushort)r;
}

__device__ inline float bflo(uint g) { return __uint_as_float(g << 16); }
__device__ inline float bfhi(uint g) { return __uint_as_float(g & 0xffff0000u); }

// ---------------- edge pass 1: XCD-partitioned packed histogram -------------
// packed[p*n + c]: bits[39:0] = sum of w (2^-25 fixed pt); bits[63:40] = count.
// Partition p = blockIdx & 7 -> with round-robin XCD dispatch, each partition's
// 400 KB array stays in one XCD's L2 (no cross-XCD atomic ping-pong).
// rank[i] = arrival rank within (partition, dst-node).

__global__ __launch_bounds__(256) void k_pass1(const int* __restrict__ col,
                                               const float* __restrict__ w,
                                               ull* __restrict__ packed,
                                               int* __restrict__ rank, int e, int n) {
    int i = blockIdx.x * 256 + threadIdx.x;
    if (i >= e) return;
    int part = blockIdx.x & (NPART - 1);
    int c = col[i];
    ull fx = (ull)(uint)(w[i] * FIXS + 0.5f);
    ull u = atomicAdd(&packed[(size_t)part * n + c], (1ULL << 40) | fx);
    rank[i] = (int)(u >> 40);
}

// ---------------- scan1: dinv + per-block inclusive scan of total counts ----

__global__ __launch_bounds__(256) void k_scan1(const ull* __restrict__ packed,
                                               float* __restrict__ dinv,
                                               int* __restrict__ incl,
                                               int* __restrict__ bsum, int n) {
    int i = blockIdx.x * 256 + threadIdx.x;
    int lane = threadIdx.x & 63;
    int wid  = threadIdx.x >> 6;
    int v = 0;
    if (i < n) {
        ull wtot = 0;
#pragma unroll
        for (int p = 0; p < NPART; ++p) {
            ull pk = packed[(size_t)p * n + i];
            v += (int)(pk >> 40);
            wtot += pk & FIXM;
        }
        float deg = 1.0f + (float)((double)wtot * (1.0 / 33554432.0));
        dinv[i] = rsqrtf(fmaxf(deg, 1e-12f));
    }
    int s = v;
#pragma unroll
    for (int off = 1; off < 64; off <<= 1) {
        int t = __shfl_up(s, off);
        if (lane >= off) s += t;
    }
    __shared__ int wsum[4];
    if (lane == 63) wsum[wid] = s;
    __syncthreads();
    int wo = 0;
    for (int w2 = 0; w2 < wid; ++w2) wo += wsum[w2];
    s += wo;
    if (i < n) incl[i] = s;
    if (threadIdx.x == 255) bsum[blockIdx.x] = s;
}

__global__ __launch_bounds__(256) void k_scan2(const int* __restrict__ bsum,
                                               int* __restrict__ boff, int nb) {
    int i = threadIdx.x;
    int lane = i & 63;
    int wid  = i >> 6;
    int v = (i < nb) ? bsum[i] : 0;
    int s = v;
#pragma unroll
    for (int off = 1; off < 64; off <<= 1) {
        int t = __shfl_up(s, off);
        if (lane >= off) s += t;
    }
    __shared__ int wsum[4];
    if (lane == 63) wsum[wid] = s;
    __syncthreads();
    int wo = 0;
    for (int w2 = 0; w2 < wid; ++w2) wo += wsum[w2];
    s += wo;
    if (i < nb) boff[i] = s - v;   // exclusive
}

// ptr[i] = global segment base; poffs[p][i] = base + counts of partitions < p

__global__ __launch_bounds__(256) void k_scan3(const ull* __restrict__ packed,
                                               const int* __restrict__ incl,
                                               const int* __restrict__ boff,
                                               int* __restrict__ ptr,
                                               int* __restrict__ poffs, int n, int e) {
    int i = blockIdx.x * 256 + threadIdx.x;
    if (i > n) return;
    if (i == n) { ptr[i] = e; return; }
    int cnt[NPART];
    int tot = 0;
#pragma unroll
    for (int p = 0; p < NPART; ++p) {
        cnt[p] = (int)(packed[(size_t)p * n + i] >> 40);
        tot += cnt[p];
    }
    int base = incl[i] - tot + boff[i >> 8];
    ptr[i] = base;
    int run = base;
#pragma unroll
    for (int p = 0; p < NPART; ++p) {
        poffs[(size_t)p * n + i] = run;
        run += cnt[p];
    }
}

// ---------------- edge pass 2: atomic-free CSR fill -------------------------

__global__ __launch_bounds__(256) void k_pass2(const int* __restrict__ row,
                                               const int* __restrict__ col,
                                               const float* __restrict__ w,
                                               const float* __restrict__ dinv,
                                               const int* __restrict__ poffs,
                                               const int* __restrict__ rank,
                                               int2* __restrict__ csr, int e, int n) {
    int i = blockIdx.x * 256 + threadIdx.x;
    if (i >= e) return;
    int part = blockIdx.x & (NPART - 1);
    int r = row[i], c = col[i];
    float v = dinv[r] * w[i];
    csr[poffs[(size_t)part * n + c] + rank[i]] = make_int2(r, __float_as_int(v));
}

// ---------------- MFMA GEMM: xw[n][d] = sum_k h[n][k]*W[d][k], bf16 out -----

#define LDW 136

__global__ __launch_bounds__(256) void k_gemm(const float* __restrict__ h,
                                              const float* __restrict__ W,
                                              ushort* __restrict__ xw, int n) {
    __shared__ ushort Wl[128 * LDW];
    __shared__ ushort Hl[64 * LDW];

    const int t   = threadIdx.x;
    const int gn0 = blockIdx.x * 64;

    for (int i = t; i < 4096; i += 256) {
        int d  = i >> 5;
        int k4 = (i & 31) * 4;
        float4 wv = *(const float4*)(W + d * D + k4);
        ushort4 p;
        p.x = f2bf(wv.x); p.y = f2bf(wv.y); p.z = f2bf(wv.z); p.w = f2bf(wv.w);
        *(ushort4*)(Wl + d * LDW + k4) = p;
    }
    for (int i = t; i < 2048; i += 256) {
        int r  = i >> 5;
        int k4 = (i & 31) * 4;
        int gn = gn0 + r;
        float4 hv = (gn < n) ? *(const float4*)(h + (size_t)gn * D + k4)
                             : make_float4(0.f, 0.f, 0.f, 0.f);
        ushort4 p;
        p.x = f2bf(hv.x); p.y = f2bf(hv.y); p.z = f2bf(hv.z); p.w = f2bf(hv.w);
        *(ushort4*)(Hl + r * LDW + k4) = p;
    }
    __syncthreads();

    const int wave  = t >> 6;
    const int lane  = t & 63;
    const int quad  = lane >> 4;
    const int l15   = lane & 15;
    const int nbase = wave * 32;

    f32x4 acc[4][2];
#pragma unroll
    for (int mt = 0; mt < 4; ++mt)
#pragma unroll
        for (int nt = 0; nt < 2; ++nt) acc[mt][nt] = (f32x4)(0.0f);

#pragma unroll
    for (int kc = 0; kc < 4; ++kc) {
        int ko = kc * 32 + quad * 8;
        bf16x8 a[4], b[2];
#pragma unroll
        for (int mt = 0; mt < 4; ++mt)
            a[mt] = *(const bf16x8*)(Hl + (mt * 16 + l15) * LDW + ko);
#pragma unroll
        for (int nt = 0; nt < 2; ++nt)
            b[nt] = *(const bf16x8*)(Wl + (nbase + nt * 16 + l15) * LDW + ko);
#pragma unroll
        for (int mt = 0; mt < 4; ++mt)
#pragma unroll
            for (int nt = 0; nt < 2; ++nt)
                acc[mt][nt] = __builtin_amdgcn_mfma_f32_16x16x32_bf16(
                    a[mt], b[nt], acc[mt][nt], 0, 0, 0);
    }
    __syncthreads();

#pragma unroll
    for (int mt = 0; mt < 4; ++mt)
#pragma unroll
        for (int nt = 0; nt < 2; ++nt)
#pragma unroll
            for (int r = 0; r < 4; ++r)
                Hl[(mt * 16 + quad * 4 + r) * LDW + nbase + nt * 16 + l15] =
                    f2bf(acc[mt][nt][r]);
    __syncthreads();

    for (int i = t; i < 1024; i += 256) {
        int r = i >> 4, seg = i & 15;
        int gn = gn0 + r;
        if (gn < n) {
            uint4 v = *(const uint4*)(Hl + r * LDW + seg * 8);
            *(uint4*)(xw + (size_t)gn * D + seg * 8) = v;
        }
    }
}

// ---------------- fused pull-aggregate + bias + LN + ReLU + residual --------
// One 64-lane wave per node; lanes 0-31 / 32-63 process two independent edge
// streams of the SAME node (4 features/lane, uint2 gathers). 4-way unroll per
// half => 8 edges in flight/iter.

__global__ __launch_bounds__(256) void k_pull_ln(const ushort* __restrict__ xw,
                                                 const int* __restrict__ ptr,
                                                 const int2* __restrict__ csr,
                                                 const float* __restrict__ dinv,
                                                 const float* __restrict__ bias,
                                                 const float* __restrict__ gamma,
                                                 const float* __restrict__ beta,
                                                 const float* __restrict__ identity,
                                                 float* __restrict__ hout,
                                                 int n, int relu) {
    int node = blockIdx.x * 4 + (threadIdx.x >> 6);
    if (node >= n) return;
    int lane = threadIdx.x & 63;
    int half = lane >> 5;
    int l    = lane & 31;
    int o    = l * 4;

    float a0 = 0.f, a1 = 0.f, a2 = 0.f, a3 = 0.f;

    int ebeg = ptr[node];
    int eend = ptr[node + 1];
    int e = ebeg + half;
    for (; e + 6 < eend; e += 8) {
        int2 eA = csr[e], eB = csr[e + 2], eC = csr[e + 4], eD2 = csr[e + 6];
        uint2 gA = *(const uint2*)(xw + (size_t)eA.x * D + o);
        uint2 gB = *(const uint2*)(xw + (size_t)eB.x * D + o);
        uint2 gC = *(const uint2*)(xw + (size_t)eC.x * D + o);
        uint2 gD = *(const uint2*)(xw + (size_t)eD2.x * D + o);
        float nA = __int_as_float(eA.y), nB = __int_as_float(eB.y);
        float nC = __int_as_float(eC.y), nD = __int_as_float(eD2.y);
        a0 += nA * bflo(gA.x) + nB * bflo(gB.x);
        a1 += nA * bfhi(gA.x) + nB * bfhi(gB.x);
        a2 += nA * bflo(gA.y) + nB * bflo(gB.y);
        a3 += nA * bfhi(gA.y) + nB * bfhi(gB.y);
        a0 += nC * bflo(gC.x) + nD * bflo(gD.x);
        a1 += nC * bfhi(gC.x) + nD * bfhi(gD.x);
        a2 += nC * bflo(gC.y) + nD * bflo(gD.y);
        a3 += nC * bfhi(gC.y) + nD * bfhi(gD.y);
    }
    for (; e < eend; e += 2) {
        int2 eA = csr[e];
        uint2 gA = *(const uint2*)(xw + (size_t)eA.x * D + o);
        float nA = __int_as_float(eA.y);
        a0 += nA * bflo(gA.x);
        a1 += nA * bfhi(gA.x);
        a2 += nA * bflo(gA.y);
        a3 += nA * bfhi(gA.y);
    }

    a0 += __shfl_xor(a0, 32);
    a1 += __shfl_xor(a1, 32);
    a2 += __shfl_xor(a2, 32);
    a3 += __shfl_xor(a3, 32);

    float di = dinv[node];
    uint2 ps = *(const uint2*)(xw + (size_t)node * D + o);
    float4 bb = *(const float4*)(bias + o);
    a0 = bb.x + di * (di * bflo(ps.x) + a0);
    a1 = bb.y + di * (di * bfhi(ps.x) + a1);
    a2 = bb.z + di * (di * bflo(ps.y) + a2);
    a3 = bb.w + di * (di * bfhi(ps.y) + a3);

    // LayerNorm over 128 features: reduce across 32 lanes (halves identical)
    float s = (a0 + a1) + (a2 + a3);
#pragma unroll
    for (int off = 16; off; off >>= 1) s += __shfl_xor(s, off);
    float mu = s * (1.0f / 128.0f);
    float d0 = a0 - mu, d1 = a1 - mu, d2 = a2 - mu, d3 = a3 - mu;
    float vs = (d0 * d0 + d1 * d1) + (d2 * d2 + d3 * d3);
#pragma unroll
    for (int off = 16; off; off >>= 1) vs += __shfl_xor(vs, off);
    float rs = rsqrtf(vs * (1.0f / 128.0f) + 1e-5f);

    float4 g  = *(const float4*)(gamma + o);
    float4 b2 = *(const float4*)(beta + o);
    float4 id = *(const float4*)(identity + (size_t)node * D + o);
    float o0 = d0 * rs * g.x + b2.x;
    float o1 = d1 * rs * g.y + b2.y;
    float o2 = d2 * rs * g.z + b2.z;
    float o3 = d3 * rs * g.w + b2.w;
    if (relu) {
        o0 = fmaxf(o0, 0.0f); o1 = fmaxf(o1, 0.0f);
        o2 = fmaxf(o2, 0.0f); o3 = fmaxf(o3, 0.0f);
    }
    if (half == 0)
        *(float4*)(hout + (size_t)node * D + o) =
            make_float4(o0 + id.x, o1 + id.y, o2 + id.z, o3 + id.w);
}

// ---------------- launch ----------------

extern "C" void kernel_launch(void* const* d_in, const int* in_sizes, int n_in,
                              void* d_out, int out_size, void* d_ws, size_t ws_size,
                              hipStream_t stream) {
    const float* x      = (const float*)d_in[0];
    const int*   ei     = (const int*)d_in[1];
    const float* ew     = (const float*)d_in[2];
    const float* Ws     = (const float*)d_in[3];
    const float* bs     = (const float*)d_in[4];
    const float* gammas = (const float*)d_in[5];
    const float* betas  = (const float*)d_in[6];
    float* out = (float*)d_out;

    const int N = in_sizes[0] / D;
    const int E = in_sizes[2];
    const int* row = ei;
    const int* col = ei + E;

    // workspace layout (8-byte types first)
    char* w8 = (char*)d_ws;
    ull*   packed = (ull*)w8;    w8 += sizeof(ull) * (size_t)N * NPART;
    int2*  csr    = (int2*)w8;   w8 += sizeof(int2) * E;
    float* dinv   = (float*)w8;  w8 += sizeof(float) * N;
    int*   incl   = (int*)w8;    w8 += sizeof(int) * N;
    int*   bsum   = (int*)w8;    w8 += sizeof(int) * 256;
    int*   boff   = (int*)w8;    w8 += sizeof(int) * 256;
    int*   ptr    = (int*)w8;    w8 += sizeof(int) * (N + 1);
    int*   poffs  = (int*)w8;    w8 += sizeof(int) * (size_t)N * NPART;
    int*   rank   = (int*)w8;    w8 += sizeof(int) * E;
    float* buf1   = (float*)w8;  w8 += sizeof(float) * (size_t)N * D;
    ushort* xwb   = (ushort*)w8; w8 += sizeof(ushort) * (size_t)N * D;

    dim3 blk(256);
    int gN1   = (N + 256) / 256;
    int gE    = (E + 255) / 256;
    int nb    = (N + 255) / 256;
    int gGemm = (N + 63) / 64;
    int gPull = (N + 3) / 4;

    hipMemsetAsync(packed, 0, sizeof(ull) * (size_t)N * NPART, stream);
    k_pass1<<<gE, blk, 0, stream>>>(col, ew, packed, rank, E, N);
    k_scan1<<<nb, blk, 0, stream>>>(packed, dinv, incl, bsum, N);
    k_scan2<<<1, blk, 0, stream>>>(bsum, boff, nb);
    k_scan3<<<gN1, blk, 0, stream>>>(packed, incl, boff, ptr, poffs, N, E);
    k_pass2<<<gE, blk, 0, stream>>>(row, col, ew, dinv, poffs, rank, csr, E, N);

    // layer 0: h = x -> out
    k_gemm<<<gGemm, blk, 0, stream>>>(x, Ws, xwb, N);
    k_pull_ln<<<gPull, blk, 0, stream>>>(xwb, ptr, csr, dinv,
                                         bs, gammas, betas, x, out, N, 1);
    // layer 1: h = out -> buf1
    k_gemm<<<gGemm, blk, 0, stream>>>(out, Ws + 16384, xwb, N);
    k_pull_ln<<<gPull, blk, 0, stream>>>(xwb, ptr, csr, dinv,
                                         bs + D, gammas + D, betas + D, out, buf1, N, 1);
    // layer 2: h = buf1 -> out
    k_gemm<<<gGemm, blk, 0, stream>>>(buf1, Ws + 32768, xwb, N);
    k_pull_ln<<<gPull, blk, 0, stream>>>(xwb, ptr, csr, dinv,
                                         bs + 2 * D, gammas + 2 * D, betas + 2 * D,
                                         buf1, out, N, 0);
}